// Round 1
// baseline (1324.118 us; speedup 1.0000x reference)
//
#include <hip/hip_runtime.h>
#include <math.h>

using u16 = unsigned short;
typedef __attribute__((ext_vector_type(8))) short short8;
typedef __attribute__((ext_vector_type(4))) float f32x4;

// B=8, C=512, N=4096, GP=4 -> G=32 groups, NG=1024, F=2048
constexpr long kPLANE = 1024l * 512;     // elems per (g) plane, T-layout (n, c)
constexpr long SZW    = 512l * 512;
constexpr long MB     = 1l << 20;

__device__ __forceinline__ float bf2f(u16 u) {
  return __uint_as_float(((unsigned int)u) << 16);
}
__device__ __forceinline__ u16 f2bf(float f) {
  unsigned int x = __float_as_uint(f);
  x += 0x7fffu + ((x >> 16) & 1u);
  return (u16)(x >> 16);
}

// async 16B global -> LDS DMA (global_load_lds_dwordx4).
// LDS dest must be linear: wave-uniform base + lane*16 (our staging layout is
// byte-offset tid*16, which satisfies this).
__device__ __forceinline__ void gld16(const u16* g, u16* l) {
  __builtin_amdgcn_global_load_lds(
      (const __attribute__((address_space(1))) unsigned int*)g,
      (__attribute__((address_space(3))) unsigned int*)l, 16, 0, 0);
}

// ---------------------------------------------------------------------------
// Unified MFMA GEMM (NT form): Out[g][m][n] = epi( scale * sum_k A[m][k]*B[n][k] )
// A (M x K) bf16 K-contig, B (N x K) bf16 K-contig. 128x128 tile, BK=32,
// 4 waves each 64x64 via 4x4 v_mfma_f32_16x16x32_bf16.
// Double-buffered LDS staging via async global_load_lds (m97 structure):
// issue next tile's DMA, ds_read + MFMA current, barrier (drains vmcnt).
// Operands swapped in mfma so each lane holds 4 consecutive n at fixed m ->
// ushort4 epilogue stores.
// epi: *rowscale[g][m] -> *pmul[g][m][n] -> +bias[n] -> +resid[g][m][n] -> act
// act: 0 none, 1 relu, 2 relu+1 (phi). pmul may alias Out.
// ---------------------------------------------------------------------------
__global__ __launch_bounds__(256) void gemm_mfma(
    const u16* __restrict__ A, long sA, int amask,
    const u16* __restrict__ B, long sB, int bmask,
    u16* __restrict__ Out, long sO,
    int M, int Nn, int K, float scale, int act,
    const float* __restrict__ bias,
    const float* __restrict__ rowscale, long sRS,
    const u16* __restrict__ pmul, const u16* __restrict__ resid)
{
  int g = blockIdx.z;
  const u16* Ag = A + (long)(g & amask) * sA;
  const u16* Bg = B + (long)(g & bmask) * sB;
  u16* Og = Out + (long)g * sO;
  int m0 = blockIdx.y * 128, n0 = blockIdx.x * 128;

  __shared__ __align__(16) u16 As[2][128 * 32];
  __shared__ __align__(16) u16 Bs[2][128 * 32];

  int tid = threadIdx.x;
  int w = tid >> 6, L = tid & 63;
  int wm = (w >> 1) * 64, wn = (w & 1) * 64;
  int l15 = L & 15, l4 = L >> 4;

  f32x4 acc[4][4] = {};

  // staging: 512 16B-chunks per 128x32 tile; thread covers chunks tid, tid+256.
  // LDS byte offset of chunk c is c*16 (linear) -> valid global_load_lds dest.
  int r0 = tid >> 2, r1 = r0 + 64;
  int kk = (tid & 3) * 8;
  int s0 = r0 * 32 + kk, s1 = r1 * 32 + kk;   // == tid*8, tid*8+2048 (elems)
  const u16* gA0 = Ag + (long)(m0 + r0) * K + kk;
  const u16* gA1 = Ag + (long)(m0 + r1) * K + kk;
  const u16* gB0 = Bg + (long)(n0 + r0) * K + kk;
  const u16* gB1 = Bg + (long)(n0 + r1) * K + kk;

  // preload tile 0 into LDS buffer 0 (async DMA; barrier drains vmcnt)
  gld16(gA0, &As[0][s0]); gld16(gA1, &As[0][s1]);
  gld16(gB0, &Bs[0][s0]); gld16(gB1, &Bs[0][s1]);
  __syncthreads();

  int nsteps = K >> 5;
  for (int ks = 0; ks < nsteps; ++ks) {
    int cur = ks & 1;
    if (ks + 1 < nsteps) {             // issue async prefetch of next K-tile
      int nxt = cur ^ 1;
      int ko = (ks + 1) << 5;
      gld16(gA0 + ko, &As[nxt][s0]); gld16(gA1 + ko, &As[nxt][s1]);
      gld16(gB0 + ko, &Bs[nxt][s0]); gld16(gB1 + ko, &Bs[nxt][s1]);
    }
    short8 af[4], bf[4];
#pragma unroll
    for (int mi = 0; mi < 4; ++mi)
      af[mi] = *(const short8*)&As[cur][(wm + mi * 16 + l15) * 32 + l4 * 8];
#pragma unroll
    for (int ni = 0; ni < 4; ++ni)
      bf[ni] = *(const short8*)&Bs[cur][(wn + ni * 16 + l15) * 32 + l4 * 8];
#pragma unroll
    for (int mi = 0; mi < 4; ++mi)
#pragma unroll
      for (int ni = 0; ni < 4; ++ni)
        acc[mi][ni] = __builtin_amdgcn_mfma_f32_16x16x32_bf16(bf[ni], af[mi], acc[mi][ni], 0, 0, 0);
    __syncthreads();                   // drains vmcnt(0): prefetch landed
  }

  // epilogue (operand-swapped D): lane holds n = nb..nb+3 at fixed m
  //   m = m0+wm+mi*16+l15 ; nb = n0+wn+ni*16+l4*4
#pragma unroll
  for (int mi = 0; mi < 4; ++mi) {
    int m = m0 + wm + mi * 16 + l15;
    float rs = rowscale ? rowscale[(long)g * sRS + m] : 1.f;
    float srs = scale * rs;
#pragma unroll
    for (int ni = 0; ni < 4; ++ni) {
      int nb = n0 + wn + ni * 16 + l4 * 4;
      long off = (long)m * Nn + nb;
      float v[4];
#pragma unroll
      for (int r = 0; r < 4; ++r) v[r] = acc[mi][ni][r] * srs;
      if (pmul) {
        ushort4 pm = *(const ushort4*)&pmul[(long)g * sO + off];
        v[0] *= bf2f(pm.x); v[1] *= bf2f(pm.y); v[2] *= bf2f(pm.z); v[3] *= bf2f(pm.w);
      }
      if (bias) {
        float4 bi = *(const float4*)&bias[nb];
        v[0] += bi.x; v[1] += bi.y; v[2] += bi.z; v[3] += bi.w;
      }
      if (resid) {
        ushort4 rd = *(const ushort4*)&resid[(long)g * sO + off];
        v[0] += bf2f(rd.x); v[1] += bf2f(rd.y); v[2] += bf2f(rd.z); v[3] += bf2f(rd.w);
      }
      if (act == 1) {
#pragma unroll
        for (int r = 0; r < 4; ++r) v[r] = fmaxf(v[r], 0.f);
      } else if (act == 2) {
#pragma unroll
        for (int r = 0; r < 4; ++r) v[r] = fmaxf(v[r], 0.f) + 1.f;
      }
      ushort4 o; o.x = f2bf(v[0]); o.y = f2bf(v[1]); o.z = f2bf(v[2]); o.w = f2bf(v[3]);
      *(ushort4*)&Og[off] = o;
    }
  }
}

// fp32 -> bf16 flat cast
__global__ __launch_bounds__(256) void castf2b(
    const float* __restrict__ src, u16* __restrict__ dst, int n)
{
  int i = blockIdx.x * 256 + threadIdx.x;
  if (i < n) dst[i] = f2bf(src[i]);
}

// gxT[gp*8+b][n][c] = feat[b][c][4n+gp]  (fp32 -> bf16). grid(32,16,8) block(32,8)
__global__ __launch_bounds__(256) void gather_feat(
    const float* __restrict__ feat, u16* __restrict__ gxT)
{
  __shared__ float t[32][132];
  int b = blockIdx.z, c0 = blockIdx.y * 32, nf0 = blockIdx.x * 128;
  int tx = threadIdx.x, ty = threadIdx.y;
  for (int r = ty; r < 32; r += 8)
    *(float4*)&t[r][tx * 4] = *(const float4*)&feat[((long)b * 512 + c0 + r) * 4096 + nf0 + tx * 4];
  __syncthreads();
  int n0o = nf0 >> 2;
  for (int gp = 0; gp < 4; ++gp) {
    long gbase = (long)(gp * 8 + b) * kPLANE;
    for (int jr = ty; jr < 32; jr += 8)
      gxT[gbase + (long)(n0o + jr) * 512 + c0 + tx] = f2bf(t[tx][jr * 4 + gp]);
  }
}

// out[g][c][n] = in[g][n][c] * (alpha ? alpha[g][n] : 1). grid(32,16,G) block(32,8)
__global__ __launch_bounds__(256) void transpose_b(
    const u16* __restrict__ in, u16* __restrict__ out, const float* __restrict__ alpha)
{
  int g = blockIdx.z;
  const u16* I = in + (long)g * kPLANE;
  u16* O = out + (long)g * kPLANE;
  __shared__ u16 t[32][33];
  int n0 = blockIdx.x * 32, c0 = blockIdx.y * 32;
  int tx = threadIdx.x, ty = threadIdx.y;
  for (int r = ty; r < 32; r += 8) t[r][tx] = I[(long)(n0 + r) * 512 + c0 + tx];
  __syncthreads();
  float al = alpha ? alpha[(long)g * 1024 + n0 + tx] : 1.f;
  for (int r = ty; r < 32; r += 8)
    O[(long)(c0 + r) * 1024 + n0 + tx] = f2bf(bf2f(t[tx][r]) * al);
}

// out[g][c] = scale * sum_n X[g][n][c] * (alpha ? alpha[g][n] : 1). grid(2,G)
__global__ __launch_bounds__(256) void colsum(
    const u16* __restrict__ X, long sX, const float* __restrict__ alpha,
    float* __restrict__ out, float scale)
{
  int g = blockIdx.y;
  int c = blockIdx.x * 256 + threadIdx.x;
  const u16* Xg = X + (long)g * sX;
  float s = 0.f;
  for (int n = 0; n < 1024; ++n)
    s += bf2f(Xg[(long)n * 512 + c]) * (alpha ? alpha[(long)g * 1024 + n] : 1.f);
  out[(long)g * 512 + c] = s * scale;
}

// out[g][n] = f( sum_c X[g][n][c] * w[(g&wmask)][c] ). mode1: 1/(x+1e-6). grid(256,G)
__global__ __launch_bounds__(256) void rowdot(
    const u16* __restrict__ X, long sX, const float* __restrict__ w, int wmask,
    float* __restrict__ out, int mode)
{
  int g = blockIdx.y;
  int n = blockIdx.x * 4 + (threadIdx.x >> 6);
  int L = threadIdx.x & 63;
  const u16* row = X + (long)g * sX + (long)n * 512;
  short8 xv = *(const short8*)&row[L * 8];
  const float* wg = w + (long)(g & wmask) * 512;
  float4 w0 = *(const float4*)&wg[L * 8];
  float4 w1 = *(const float4*)&wg[L * 8 + 4];
  float s = bf2f((u16)xv[0]) * w0.x + bf2f((u16)xv[1]) * w0.y +
            bf2f((u16)xv[2]) * w0.z + bf2f((u16)xv[3]) * w0.w +
            bf2f((u16)xv[4]) * w1.x + bf2f((u16)xv[5]) * w1.y +
            bf2f((u16)xv[6]) * w1.z + bf2f((u16)xv[7]) * w1.w;
#pragma unroll
  for (int off = 32; off >= 1; off >>= 1) s += __shfl_down(s, off);
  if (L == 0) out[(long)g * 1024 + n] = mode ? 1.f / (s + 1e-6f) : s;
}

// alpha[g][n] = softmax_n(sc[g])[n] * 1024. grid(G)
__global__ __launch_bounds__(256) void softmax_row(
    const float* __restrict__ sc, float* __restrict__ out)
{
  int g = blockIdx.x, tid = threadIdx.x;
  const float* s = sc + (long)g * 1024;
  float* o = out + (long)g * 1024;
  __shared__ float red[256];
  float lm = -3.4e38f;
  for (int n = tid; n < 1024; n += 256) lm = fmaxf(lm, s[n]);
  red[tid] = lm; __syncthreads();
  for (int st = 128; st; st >>= 1) { if (tid < st) red[tid] = fmaxf(red[tid], red[tid + st]); __syncthreads(); }
  float mx = red[0]; __syncthreads();
  float ls = 0.f;
  for (int n = tid; n < 1024; n += 256) ls += __expf(s[n] - mx);
  red[tid] = ls; __syncthreads();
  for (int st = 128; st; st >>= 1) { if (tid < st) red[tid] += red[tid + st]; __syncthreads(); }
  float inv = 1024.f / red[0];
  for (int n = tid; n < 1024; n += 256) o[n] = __expf(s[n] - mx) * inv;
}

// LayerNorm over 512-wide contiguous rows, bf16 in/out, fp32 gamma/beta.
__global__ __launch_bounds__(256) void ln_rows(
    const u16* __restrict__ X, const float* __restrict__ gamma,
    const float* __restrict__ beta, u16* __restrict__ Out, int relu)
{
  long m = blockIdx.x;
  const u16* x = X + m * 512;
  u16* o = Out + m * 512;
  int tid = threadIdx.x;
  ushort2 u2 = *(const ushort2*)&x[tid * 2];
  float v0 = bf2f(u2.x), v1 = bf2f(u2.y);
  __shared__ float red[256];
  red[tid] = v0 + v1; __syncthreads();
  for (int st = 128; st; st >>= 1) { if (tid < st) red[tid] += red[tid + st]; __syncthreads(); }
  float mu = red[0] * (1.f / 512.f);
  __syncthreads();
  float d0 = v0 - mu, d1 = v1 - mu;
  red[tid] = d0 * d0 + d1 * d1; __syncthreads();
  for (int st = 128; st; st >>= 1) { if (tid < st) red[tid] += red[tid + st]; __syncthreads(); }
  float rs = rsqrtf(red[0] * (1.f / 512.f) + 1e-6f);
  float2 gm = *(const float2*)&gamma[tid * 2];
  float2 bt = *(const float2*)&beta[tid * 2];
  float o0 = d0 * rs * gm.x + bt.x, o1 = d1 * rs * gm.y + bt.y;
  if (relu) { o0 = fmaxf(o0, 0.f); o1 = fmaxf(o1, 0.f); }
  ushort2 r; r.x = f2bf(o0); r.y = f2bf(o1);
  *(ushort2*)&o[tid * 2] = r;
}

// gx2T[g2][m][*] = t_saT[(m&3)*8+(g2&7)][(g2>>3)*256+(m>>2)][*]. grid 32768
__global__ __launch_bounds__(256) void gather_x2(
    const u16* __restrict__ T, u16* __restrict__ X2)
{
  int bid = blockIdx.x;
  int g2 = bid >> 10, m = bid & 1023;
  long src = ((long)((m & 3) * 8 + (g2 & 7)) * 1024 + (g2 >> 3) * 256 + (m >> 2)) * 512;
  long dst = ((long)g2 * 1024 + m) * 512;
  int t2 = threadIdx.x * 2;
  *(ushort2*)&X2[dst + t2] = *(const ushort2*)&T[src + t2];
}

// ybar = mean over 24 planes (bf16 in, fp32 out). grid 2048
__global__ __launch_bounds__(256) void ybar_k(
    const u16* __restrict__ Y, float* __restrict__ yb)
{
  long idx = (long)blockIdx.x * 256 + threadIdx.x;
  float s = 0.f;
#pragma unroll
  for (int g = 0; g < 24; ++g) s += bf2f(Y[(long)g * kPLANE + idx]);
  yb[idx] = s * (1.f / 24.f);
}

// h_first[b][n][c] = gx2T[b][n][c] + ybar[n][c]*phiF[b][n][c]. grid 16384
__global__ __launch_bounds__(256) void hfirst_k(
    const u16* __restrict__ gx2, const u16* __restrict__ phiF,
    const float* __restrict__ yb, u16* __restrict__ h)
{
  long idx = (long)blockIdx.x * 256 + threadIdx.x;
  long p = idx & (kPLANE - 1);
  h[idx] = f2bf(bf2f(gx2[idx]) + yb[p] * bf2f(phiF[idx]));
}

// out[b][c][gp2*1024+m] = (gp2==0 ? crossT[b] : gx2T[g2])[m][c]. grid(32,16,32) block(32,8)
__global__ __launch_bounds__(256) void assemble_t(
    const u16* __restrict__ gx2T, const u16* __restrict__ crossT,
    float* __restrict__ out)
{
  int g2 = blockIdx.z, gp2 = g2 >> 3, b = g2 & 7;
  const u16* S = (gp2 == 0) ? crossT + (long)b * kPLANE : gx2T + (long)g2 * kPLANE;
  __shared__ u16 t[32][33];
  int m0 = blockIdx.x * 32, c0 = blockIdx.y * 32;
  int tx = threadIdx.x, ty = threadIdx.y;
  for (int r = ty; r < 32; r += 8) t[r][tx] = S[(long)(m0 + r) * 512 + c0 + tx];
  __syncthreads();
  for (int r = ty; r < 32; r += 8)
    out[((long)b * 512 + c0 + r) * 4096 + gp2 * 1024 + m0 + tx] = bf2f(t[tx][r]);
}

extern "C" void kernel_launch(void* const* d_in, const int* in_sizes, int n_in,
                              void* d_out, int out_size, void* d_ws, size_t ws_size,
                              hipStream_t stream)
{
  const float* feat = (const float*)d_in[0];
  const float* tg1 = (const float*)d_in[4];  const float* tb1 = (const float*)d_in[5];
  const float* tf1b = (const float*)d_in[7];
  const float* tf2b = (const float*)d_in[9];
  const float* tg2 = (const float*)d_in[10]; const float* tb2 = (const float*)d_in[11];
  const float* cg1 = (const float*)d_in[16]; const float* cb1 = (const float*)d_in[17];
  const float* cf1b = (const float*)d_in[19];
  const float* cf2b = (const float*)d_in[21];
  const float* cg2 = (const float*)d_in[22]; const float* cb2 = (const float*)d_in[23];

  // ---- ws layout (peak 112 MiB) ----
  char* wsb = (char*)d_ws;
  u16* WP = (u16*)wsb;                 // 7 proj weights (d,c) bf16: 3.5 MiB
  u16* WF = (u16*)(wsb + 4 * MB);      // 4 FFN weights bf16: 8 MiB
  float* SM = (float*)(wsb + 12 * MB); // fp32 smalls
  float* QG = SM;                      // 32*512
  float* SC = SM + 16384;              // 32*1024
  float* AL = SM + 49152;              // 32*1024
  float* KS = SM + 81920;              // 32*512
  float* Zb = SM + 98304;              // 32*1024
  float* ZR = SM + 131072;             // 24*1024
  float* YB = SM + 155648;             // 1024*512 fp32
  u16* P2 = (u16*)(wsb + 16 * MB);     // 32 planes
  u16* P3 = (u16*)(wsb + 48 * MB);     // 32 planes
  u16* P4 = (u16*)(wsb + 80 * MB);     // 32 planes (ends 112 MiB)

  // ---- d_out (64 MiB) doubles as scratch until final assemble ----
  char* ob = (char*)d_out;
  u16* KV  = (u16*)ob;                 // SA kvT: 16 MiB
  u16* GXT = (u16*)(ob + 16 * MB);     // gxT: 32 MiB (dead after y GEMM)
  u16* HID = (u16*)ob;                 // FFN hidden chunk: 64 MiB (kv+gxT dead)
  u16* KV2 = (u16*)(ob + 32 * MB);     // cross kvT: 4 MiB
  u16* PHF = (u16*)(ob + 36 * MB);     // phi_first: 8 MiB
  u16* K0S = (u16*)(ob + 44 * MB);     // k0*alpha (c,n): 8 MiB
  u16* V0S = (u16*)(ob + 52 * MB);     // v0 (c,n): 8 MiB

  u16 *WPqk = WP,           *WPv  = WP + SZW,     *WPphi = WP + 2 * SZW,
      *WPcq = WP + 3 * SZW, *WPck = WP + 4 * SZW, *WPcv  = WP + 5 * SZW,
      *WPcphi = WP + 6 * SZW;
  u16 *WF1 = WF, *WF2 = WF + 1048576, *WF3 = WF + 2097152, *WF4 = WF + 3145728;

  dim3 b256(256), bT(32, 8);
  const float rsc = 1.0f / sqrtf(512.0f);
  const long PL = kPLANE;

  // 0. weight casts (no transposes needed in NT world)
  const float* wsrc[7] = {(const float*)d_in[1], (const float*)d_in[2], (const float*)d_in[3],
                          (const float*)d_in[12], (const float*)d_in[13], (const float*)d_in[14],
                          (const float*)d_in[15]};
  for (int i = 0; i < 7; ++i)
    castf2b<<<1024, b256, 0, stream>>>(wsrc[i], WP + i * SZW, 262144);
  castf2b<<<4096, b256, 0, stream>>>((const float*)d_in[6],  WF1, 1048576);
  castf2b<<<4096, b256, 0, stream>>>((const float*)d_in[8],  WF2, 1048576);
  castf2b<<<4096, b256, 0, stream>>>((const float*)d_in[18], WF3, 1048576);
  castf2b<<<4096, b256, 0, stream>>>((const float*)d_in[20], WF4, 1048576);

  // ---------------- SA block (all tensors (g,n,c) T-layout) ----------------
  gather_feat<<<dim3(32, 16, 8), bT, 0, stream>>>(feat, GXT);
  // qT = phi(gxT . Wqk^T)
  gemm_mfma<<<dim3(4, 8, 32), b256, 0, stream>>>(GXT, PL, 31, WPqk, 0, 0, P2, PL,
      1024, 512, 512, 1.f, 2, nullptr, nullptr, 0, nullptr, nullptr);
  colsum<<<dim3(2, 32), b256, 0, stream>>>(P2, PL, nullptr, QG, 1.f / 1024.f);
  rowdot<<<dim3(256, 32), b256, 0, stream>>>(P2, PL, QG, 31, SC, 0);
  softmax_row<<<32, b256, 0, stream>>>(SC, AL);
  // vT, then transpose v and k'=q*alpha into (c,n) layout for kv GEMM
  gemm_mfma<<<dim3(4, 8, 32), b256, 0, stream>>>(GXT, PL, 31, WPv, 0, 0, P3, PL,
      1024, 512, 512, 1.f, 0, nullptr, nullptr, 0, nullptr, nullptr);
  transpose_b<<<dim3(32, 16, 32), bT, 0, stream>>>(P3, P4, nullptr);  // v
  transpose_b<<<dim3(32, 16, 32), bT, 0, stream>>>(P2, P3, AL);       // k'
  // kvT[d][c] = sum_n v[d][n] k'[c][n] * rsc
  gemm_mfma<<<dim3(4, 4, 32), b256, 0, stream>>>(P4, PL, 31, P3, PL, 31, KV, SZW,
      512, 512, 1024, rsc, 0, nullptr, nullptr, 0, nullptr, nullptr);
  colsum<<<dim3(2, 32), b256, 0, stream>>>(P2, PL, AL, KS, 1.f);
  rowdot<<<dim3(256, 32), b256, 0, stream>>>(P2, PL, KS, 31, Zb, 1);
  // phixT
  gemm_mfma<<<dim3(4, 8, 32), b256, 0, stream>>>(GXT, PL, 31, WPphi, 0, 0, P4, PL,
      1024, 512, 512, 1.f, 0, nullptr, nullptr, 0, nullptr, nullptr);
  // h_preT = qT.kvT * z[n] * phixT + gxT
  gemm_mfma<<<dim3(4, 8, 32), b256, 0, stream>>>(P2, PL, 31, KV, SZW, 31, P3, PL,
      1024, 512, 512, 1.f, 0, nullptr, Zb, 1024, P4, GXT);
  ln_rows<<<32768, b256, 0, stream>>>(P3, tg1, tb1, P2, 0);
  // FFN 512->2048->512, 2 chunks of 16384 rows (HID = full 64 MiB d_out)
  for (int ch = 0; ch < 2; ++ch) {
    const u16* Hc = P2 + (long)ch * 16 * PL;
    gemm_mfma<<<dim3(16, 128, 1), b256, 0, stream>>>(Hc, 0, 0, WF1, 0, 0, HID, 0,
        16384, 2048, 512, 1.f, 1, tf1b, nullptr, 0, nullptr, nullptr);
    gemm_mfma<<<dim3(4, 128, 1), b256, 0, stream>>>(HID, 0, 0, WF2, 0, 0,
        P3 + (long)ch * 16 * PL, 0, 16384, 512, 2048, 1.f, 0, tf2b, nullptr, 0, nullptr, Hc);
  }
  ln_rows<<<32768, b256, 0, stream>>>(P3, tg2, tb2, P2, 1);       // t_saT
  gather_x2<<<32768, b256, 0, stream>>>(P2, P4);                  // gx2T

  // ---------------- cross block ----------------
  gemm_mfma<<<dim3(4, 8, 24), b256, 0, stream>>>(P4 + 8 * PL, PL, 31, WPcq, 0, 0, P2, PL,
      1024, 512, 512, 1.f, 2, nullptr, nullptr, 0, nullptr, nullptr);        // q_restT
  gemm_mfma<<<dim3(4, 8, 24), b256, 0, stream>>>(P4 + 8 * PL, PL, 31, WPcphi, 0, 0, P3, PL,
      1024, 512, 512, 1.f, 0, nullptr, nullptr, 0, nullptr, nullptr);        // phi_restT
  gemm_mfma<<<dim3(4, 8, 8), b256, 0, stream>>>(P4, PL, 31, WPck, 0, 0, P2 + 24 * PL, PL,
      1024, 512, 512, 1.f, 2, nullptr, nullptr, 0, nullptr, nullptr);        // k0T
  gemm_mfma<<<dim3(4, 8, 8), b256, 0, stream>>>(P4, PL, 31, WPcv, 0, 0, P3 + 24 * PL, PL,
      1024, 512, 512, 1.f, 0, nullptr, nullptr, 0, nullptr, nullptr);        // v0T
  gemm_mfma<<<dim3(4, 8, 8), b256, 0, stream>>>(P4, PL, 31, WPcphi, 0, 0, PHF, PL,
      1024, 512, 512, 1.f, 0, nullptr, nullptr, 0, nullptr, nullptr);        // phi_firstT
  colsum<<<dim3(2, 8), b256, 0, stream>>>(P2 + 24 * PL, PL, nullptr, QG, 1.f / 1024.f);
  rowdot<<<dim3(256, 8), b256, 0, stream>>>(P2 + 24 * PL, PL, QG, 7, SC, 0);
  softmax_row<<<8, b256, 0, stream>>>(SC, AL);
  transpose_b<<<dim3(32, 16, 8), bT, 0, stream>>>(P2 + 24 * PL, K0S, AL);  // k0'
  transpose_b<<<dim3(32, 16, 8), bT, 0, stream>>>(P3 + 24 * PL, V0S, nullptr);
  gemm_mfma<<<dim3(4, 4, 8), b256, 0, stream>>>(V0S, PL, 31, K0S, PL, 31, KV2, SZW,
      512, 512, 1024, rsc, 0, nullptr, nullptr, 0, nullptr, nullptr);
  colsum<<<dim3(2, 8), b256, 0, stream>>>(P2 + 24 * PL, PL, AL, KS, 1.f);
  rowdot<<<dim3(256, 24), b256, 0, stream>>>(P2, PL, KS, 7, ZR, 1);
  // y_restT = q_restT.kvT2[g&7] * z[n] * phi_restT  (in-place into P3)
  gemm_mfma<<<dim3(4, 8, 24), b256, 0, stream>>>(P2, PL, 31, KV2, SZW, 7, P3, PL,
      1024, 512, 512, 1.f, 0, nullptr, ZR, 1024, P3, nullptr);
  ybar_k<<<2048, b256, 0, stream>>>(P3, YB);
  hfirst_k<<<16384, b256, 0, stream>>>(P4, PHF, YB, P2 + 24 * PL);   // h_first
  ln_rows<<<8192, b256, 0, stream>>>(P2 + 24 * PL, cg1, cb1, P3 + 24 * PL, 0);
  gemm_mfma<<<dim3(16, 64, 1), b256, 0, stream>>>(P3 + 24 * PL, 0, 0, WF3, 0, 0, HID, 0,
      8192, 2048, 512, 1.f, 1, cf1b, nullptr, 0, nullptr, nullptr);
  gemm_mfma<<<dim3(4, 64, 1), b256, 0, stream>>>(HID, 0, 0, WF4, 0, 0, P2 + 24 * PL, 0,
      8192, 512, 2048, 1.f, 0, cf2b, nullptr, 0, nullptr, P3 + 24 * PL);
  ln_rows<<<8192, b256, 0, stream>>>(P2 + 24 * PL, cg2, cb2, P3 + 24 * PL, 1); // crossT
  assemble_t<<<dim3(32, 16, 32), bT, 0, stream>>>(P4, P3 + 24 * PL, (float*)d_out);
}

// Round 2
// 1301.233 us; speedup vs baseline: 1.0176x; 1.0176x over previous
//
#include <hip/hip_runtime.h>
#include <math.h>

using u16 = unsigned short;
typedef __attribute__((ext_vector_type(8))) short short8;
typedef __attribute__((ext_vector_type(4))) float f32x4;

// B=8, C=512, N=4096, GP=4 -> G=32 groups, NG=1024, F=2048
constexpr long kPLANE = 1024l * 512;     // elems per (g) plane, T-layout (n, c)
constexpr long SZW    = 512l * 512;
constexpr long MB     = 1l << 20;

__device__ __forceinline__ float bf2f(u16 u) {
  return __uint_as_float(((unsigned int)u) << 16);
}
__device__ __forceinline__ u16 f2bf(float f) {
  unsigned int x = __float_as_uint(f);
  x += 0x7fffu + ((x >> 16) & 1u);
  return (u16)(x >> 16);
}

// ---------------------------------------------------------------------------
// Unified MFMA GEMM (NT form): Out[g][m][n] = epi( scale * sum_k A[m][k]*B[n][k] )
// A (M x K) bf16 K-contig, B (N x K) bf16 K-contig. 128x128 tile, BK=32,
// 4 waves each 64x64 via 4x4 v_mfma_f32_16x16x32_bf16.
// Register staging with DEPTH-2 prefetch: at step ks, issue loads for tile
// ks+2 (into the spare reg set), MFMA tile ks, ds_write tile ks+1 (loaded a
// full step earlier -> vmcnt wait ~free). One barrier per K-step.
// Loop hand-unrolled x2 with named reg sets (static indexing only).
// Operands swapped in mfma so each lane holds 4 consecutive n at fixed m ->
// ushort4 epilogue stores.
// epi: *rowscale[g][m] -> *pmul[g][m][n] -> +bias[n] -> +resid[g][m][n] -> act
// act: 0 none, 1 relu, 2 relu+1 (phi). pmul may alias Out.
// ---------------------------------------------------------------------------
__global__ __launch_bounds__(256) void gemm_mfma(
    const u16* __restrict__ A, long sA, int amask,
    const u16* __restrict__ B, long sB, int bmask,
    u16* __restrict__ Out, long sO,
    int M, int Nn, int K, float scale, int act,
    const float* __restrict__ bias,
    const float* __restrict__ rowscale, long sRS,
    const u16* __restrict__ pmul, const u16* __restrict__ resid)
{
  int g = blockIdx.z;
  const u16* Ag = A + (long)(g & amask) * sA;
  const u16* Bg = B + (long)(g & bmask) * sB;
  u16* Og = Out + (long)g * sO;
  int m0 = blockIdx.y * 128, n0 = blockIdx.x * 128;

  __shared__ __align__(16) u16 As[2][128 * 32];
  __shared__ __align__(16) u16 Bs[2][128 * 32];

  int tid = threadIdx.x;
  int w = tid >> 6, L = tid & 63;
  int wm = (w >> 1) * 64, wn = (w & 1) * 64;
  int l15 = L & 15, l4 = L >> 4;

  f32x4 acc[4][4] = {};

  // staging: 512 16B-chunks per 128x32 tile; thread covers chunks tid, tid+256
  int r0 = tid >> 2, r1 = r0 + 64;
  int kk = (tid & 3) * 8;
  int s0 = r0 * 32 + kk, s1 = r1 * 32 + kk;
  const u16* gA0 = Ag + (long)(m0 + r0) * K + kk;
  const u16* gA1 = Ag + (long)(m0 + r1) * K + kk;
  const u16* gB0 = Bg + (long)(n0 + r0) * K + kk;
  const u16* gB1 = Bg + (long)(n0 + r1) * K + kk;

  int nsteps = K >> 5;   // K in {512,1024,2048} -> nsteps even, >= 16

  // reg set P (pa*) and set Q (qa*)
  short8 pa0, pa1, pb0, pb1, qa0, qa1, qb0, qb1;

  // prologue: tile0 -> setP -> LDS[0]; issue tile1 -> setQ
  pa0 = *(const short8*)gA0; pa1 = *(const short8*)gA1;
  pb0 = *(const short8*)gB0; pb1 = *(const short8*)gB1;
  *(short8*)&As[0][s0] = pa0; *(short8*)&As[0][s1] = pa1;
  *(short8*)&Bs[0][s0] = pb0; *(short8*)&Bs[0][s1] = pb1;
  qa0 = *(const short8*)(gA0 + 32); qa1 = *(const short8*)(gA1 + 32);
  qb0 = *(const short8*)(gB0 + 32); qb1 = *(const short8*)(gB1 + 32);
  __syncthreads();

  // step KS: consume LDS[CUR]; HOLD_* holds tile KS+1 (write to LDS[NXT]);
  // issue tile KS+2 into OTH_* (the set whose data was written last step).
#define GSTEP(KS, CUR, NXT, HA0, HA1, HB0, HB1, OA0, OA1, OB0, OB1)            \
  {                                                                            \
    if ((KS) + 2 < nsteps) {                                                   \
      int ko = ((KS) + 2) << 5;                                                \
      OA0 = *(const short8*)(gA0 + ko); OA1 = *(const short8*)(gA1 + ko);      \
      OB0 = *(const short8*)(gB0 + ko); OB1 = *(const short8*)(gB1 + ko);      \
    }                                                                          \
    short8 af[4], bf[4];                                                       \
    _Pragma("unroll") for (int mi = 0; mi < 4; ++mi)                           \
      af[mi] = *(const short8*)&As[CUR][(wm + mi * 16 + l15) * 32 + l4 * 8];   \
    _Pragma("unroll") for (int ni = 0; ni < 4; ++ni)                           \
      bf[ni] = *(const short8*)&Bs[CUR][(wn + ni * 16 + l15) * 32 + l4 * 8];   \
    _Pragma("unroll") for (int mi = 0; mi < 4; ++mi)                           \
      _Pragma("unroll") for (int ni = 0; ni < 4; ++ni)                         \
        acc[mi][ni] = __builtin_amdgcn_mfma_f32_16x16x32_bf16(                 \
            bf[ni], af[mi], acc[mi][ni], 0, 0, 0);                             \
    if ((KS) + 1 < nsteps) {                                                   \
      *(short8*)&As[NXT][s0] = HA0; *(short8*)&As[NXT][s1] = HA1;              \
      *(short8*)&Bs[NXT][s0] = HB0; *(short8*)&Bs[NXT][s1] = HB1;              \
    }                                                                          \
    __syncthreads();                                                           \
  }

  for (int ks = 0; ks < nsteps; ks += 2) {
    GSTEP(ks,     0, 1, qa0, qa1, qb0, qb1, pa0, pa1, pb0, pb1)  // setQ=ks+1
    GSTEP(ks + 1, 1, 0, pa0, pa1, pb0, pb1, qa0, qa1, qb0, qb1)  // setP=ks+2
  }
#undef GSTEP

  // epilogue (operand-swapped D): lane holds n = nb..nb+3 at fixed m
  //   m = m0+wm+mi*16+l15 ; nb = n0+wn+ni*16+l4*4
#pragma unroll
  for (int mi = 0; mi < 4; ++mi) {
    int m = m0 + wm + mi * 16 + l15;
    float rs = rowscale ? rowscale[(long)g * sRS + m] : 1.f;
    float srs = scale * rs;
#pragma unroll
    for (int ni = 0; ni < 4; ++ni) {
      int nb = n0 + wn + ni * 16 + l4 * 4;
      long off = (long)m * Nn + nb;
      float v[4];
#pragma unroll
      for (int r = 0; r < 4; ++r) v[r] = acc[mi][ni][r] * srs;
      if (pmul) {
        ushort4 pm = *(const ushort4*)&pmul[(long)g * sO + off];
        v[0] *= bf2f(pm.x); v[1] *= bf2f(pm.y); v[2] *= bf2f(pm.z); v[3] *= bf2f(pm.w);
      }
      if (bias) {
        float4 bi = *(const float4*)&bias[nb];
        v[0] += bi.x; v[1] += bi.y; v[2] += bi.z; v[3] += bi.w;
      }
      if (resid) {
        ushort4 rd = *(const ushort4*)&resid[(long)g * sO + off];
        v[0] += bf2f(rd.x); v[1] += bf2f(rd.y); v[2] += bf2f(rd.z); v[3] += bf2f(rd.w);
      }
      if (act == 1) {
#pragma unroll
        for (int r = 0; r < 4; ++r) v[r] = fmaxf(v[r], 0.f);
      } else if (act == 2) {
#pragma unroll
        for (int r = 0; r < 4; ++r) v[r] = fmaxf(v[r], 0.f) + 1.f;
      }
      ushort4 o; o.x = f2bf(v[0]); o.y = f2bf(v[1]); o.z = f2bf(v[2]); o.w = f2bf(v[3]);
      *(ushort4*)&Og[off] = o;
    }
  }
}

// fp32 -> bf16 flat cast
__global__ __launch_bounds__(256) void castf2b(
    const float* __restrict__ src, u16* __restrict__ dst, int n)
{
  int i = blockIdx.x * 256 + threadIdx.x;
  if (i < n) dst[i] = f2bf(src[i]);
}

// gxT[gp*8+b][n][c] = feat[b][c][4n+gp]  (fp32 -> bf16). grid(32,16,8) block(32,8)
__global__ __launch_bounds__(256) void gather_feat(
    const float* __restrict__ feat, u16* __restrict__ gxT)
{
  __shared__ float t[32][132];
  int b = blockIdx.z, c0 = blockIdx.y * 32, nf0 = blockIdx.x * 128;
  int tx = threadIdx.x, ty = threadIdx.y;
  for (int r = ty; r < 32; r += 8)
    *(float4*)&t[r][tx * 4] = *(const float4*)&feat[((long)b * 512 + c0 + r) * 4096 + nf0 + tx * 4];
  __syncthreads();
  int n0o = nf0 >> 2;
  for (int gp = 0; gp < 4; ++gp) {
    long gbase = (long)(gp * 8 + b) * kPLANE;
    for (int jr = ty; jr < 32; jr += 8)
      gxT[gbase + (long)(n0o + jr) * 512 + c0 + tx] = f2bf(t[tx][jr * 4 + gp]);
  }
}

// out[g][c][n] = in[g][n][c] * (alpha ? alpha[g][n] : 1). grid(32,16,G) block(32,8)
__global__ __launch_bounds__(256) void transpose_b(
    const u16* __restrict__ in, u16* __restrict__ out, const float* __restrict__ alpha)
{
  int g = blockIdx.z;
  const u16* I = in + (long)g * kPLANE;
  u16* O = out + (long)g * kPLANE;
  __shared__ u16 t[32][33];
  int n0 = blockIdx.x * 32, c0 = blockIdx.y * 32;
  int tx = threadIdx.x, ty = threadIdx.y;
  for (int r = ty; r < 32; r += 8) t[r][tx] = I[(long)(n0 + r) * 512 + c0 + tx];
  __syncthreads();
  float al = alpha ? alpha[(long)g * 1024 + n0 + tx] : 1.f;
  for (int r = ty; r < 32; r += 8)
    O[(long)(c0 + r) * 1024 + n0 + tx] = f2bf(bf2f(t[tx][r]) * al);
}

// out[g][c] = scale * sum_n X[g][n][c] * (alpha ? alpha[g][n] : 1). grid(2,G)
__global__ __launch_bounds__(256) void colsum(
    const u16* __restrict__ X, long sX, const float* __restrict__ alpha,
    float* __restrict__ out, float scale)
{
  int g = blockIdx.y;
  int c = blockIdx.x * 256 + threadIdx.x;
  const u16* Xg = X + (long)g * sX;
  float s = 0.f;
  for (int n = 0; n < 1024; ++n)
    s += bf2f(Xg[(long)n * 512 + c]) * (alpha ? alpha[(long)g * 1024 + n] : 1.f);
  out[(long)g * 512 + c] = s * scale;
}

// out[g][n] = f( sum_c X[g][n][c] * w[(g&wmask)][c] ). mode1: 1/(x+1e-6). grid(256,G)
__global__ __launch_bounds__(256) void rowdot(
    const u16* __restrict__ X, long sX, const float* __restrict__ w, int wmask,
    float* __restrict__ out, int mode)
{
  int g = blockIdx.y;
  int n = blockIdx.x * 4 + (threadIdx.x >> 6);
  int L = threadIdx.x & 63;
  const u16* row = X + (long)g * sX + (long)n * 512;
  short8 xv = *(const short8*)&row[L * 8];
  const float* wg = w + (long)(g & wmask) * 512;
  float4 w0 = *(const float4*)&wg[L * 8];
  float4 w1 = *(const float4*)&wg[L * 8 + 4];
  float s = bf2f((u16)xv[0]) * w0.x + bf2f((u16)xv[1]) * w0.y +
            bf2f((u16)xv[2]) * w0.z + bf2f((u16)xv[3]) * w0.w +
            bf2f((u16)xv[4]) * w1.x + bf2f((u16)xv[5]) * w1.y +
            bf2f((u16)xv[6]) * w1.z + bf2f((u16)xv[7]) * w1.w;
#pragma unroll
  for (int off = 32; off >= 1; off >>= 1) s += __shfl_down(s, off);
  if (L == 0) out[(long)g * 1024 + n] = mode ? 1.f / (s + 1e-6f) : s;
}

// alpha[g][n] = softmax_n(sc[g])[n] * 1024. grid(G)
__global__ __launch_bounds__(256) void softmax_row(
    const float* __restrict__ sc, float* __restrict__ out)
{
  int g = blockIdx.x, tid = threadIdx.x;
  const float* s = sc + (long)g * 1024;
  float* o = out + (long)g * 1024;
  __shared__ float red[256];
  float lm = -3.4e38f;
  for (int n = tid; n < 1024; n += 256) lm = fmaxf(lm, s[n]);
  red[tid] = lm; __syncthreads();
  for (int st = 128; st; st >>= 1) { if (tid < st) red[tid] = fmaxf(red[tid], red[tid + st]); __syncthreads(); }
  float mx = red[0]; __syncthreads();
  float ls = 0.f;
  for (int n = tid; n < 1024; n += 256) ls += __expf(s[n] - mx);
  red[tid] = ls; __syncthreads();
  for (int st = 128; st; st >>= 1) { if (tid < st) red[tid] += red[tid + st]; __syncthreads(); }
  float inv = 1024.f / red[0];
  for (int n = tid; n < 1024; n += 256) o[n] = __expf(s[n] - mx) * inv;
}

// LayerNorm over 512-wide contiguous rows, bf16 in/out, fp32 gamma/beta.
__global__ __launch_bounds__(256) void ln_rows(
    const u16* __restrict__ X, const float* __restrict__ gamma,
    const float* __restrict__ beta, u16* __restrict__ Out, int relu)
{
  long m = blockIdx.x;
  const u16* x = X + m * 512;
  u16* o = Out + m * 512;
  int tid = threadIdx.x;
  ushort2 u2 = *(const ushort2*)&x[tid * 2];
  float v0 = bf2f(u2.x), v1 = bf2f(u2.y);
  __shared__ float red[256];
  red[tid] = v0 + v1; __syncthreads();
  for (int st = 128; st; st >>= 1) { if (tid < st) red[tid] += red[tid + st]; __syncthreads(); }
  float mu = red[0] * (1.f / 512.f);
  __syncthreads();
  float d0 = v0 - mu, d1 = v1 - mu;
  red[tid] = d0 * d0 + d1 * d1; __syncthreads();
  for (int st = 128; st; st >>= 1) { if (tid < st) red[tid] += red[tid + st]; __syncthreads(); }
  float rs = rsqrtf(red[0] * (1.f / 512.f) + 1e-6f);
  float2 gm = *(const float2*)&gamma[tid * 2];
  float2 bt = *(const float2*)&beta[tid * 2];
  float o0 = d0 * rs * gm.x + bt.x, o1 = d1 * rs * gm.y + bt.y;
  if (relu) { o0 = fmaxf(o0, 0.f); o1 = fmaxf(o1, 0.f); }
  ushort2 r; r.x = f2bf(o0); r.y = f2bf(o1);
  *(ushort2*)&o[tid * 2] = r;
}

// gx2T[g2][m][*] = t_saT[(m&3)*8+(g2&7)][(g2>>3)*256+(m>>2)][*]. grid 32768
__global__ __launch_bounds__(256) void gather_x2(
    const u16* __restrict__ T, u16* __restrict__ X2)
{
  int bid = blockIdx.x;
  int g2 = bid >> 10, m = bid & 1023;
  long src = ((long)((m & 3) * 8 + (g2 & 7)) * 1024 + (g2 >> 3) * 256 + (m >> 2)) * 512;
  long dst = ((long)g2 * 1024 + m) * 512;
  int t2 = threadIdx.x * 2;
  *(ushort2*)&X2[dst + t2] = *(const ushort2*)&T[src + t2];
}

// ybar = mean over 24 planes (bf16 in, fp32 out). grid 2048
__global__ __launch_bounds__(256) void ybar_k(
    const u16* __restrict__ Y, float* __restrict__ yb)
{
  long idx = (long)blockIdx.x * 256 + threadIdx.x;
  float s = 0.f;
#pragma unroll
  for (int g = 0; g < 24; ++g) s += bf2f(Y[(long)g * kPLANE + idx]);
  yb[idx] = s * (1.f / 24.f);
}

// h_first[b][n][c] = gx2T[b][n][c] + ybar[n][c]*phiF[b][n][c]. grid 16384
__global__ __launch_bounds__(256) void hfirst_k(
    const u16* __restrict__ gx2, const u16* __restrict__ phiF,
    const float* __restrict__ yb, u16* __restrict__ h)
{
  long idx = (long)blockIdx.x * 256 + threadIdx.x;
  long p = idx & (kPLANE - 1);
  h[idx] = f2bf(bf2f(gx2[idx]) + yb[p] * bf2f(phiF[idx]));
}

// out[b][c][gp2*1024+m] = (gp2==0 ? crossT[b] : gx2T[g2])[m][c]. grid(32,16,32) block(32,8)
__global__ __launch_bounds__(256) void assemble_t(
    const u16* __restrict__ gx2T, const u16* __restrict__ crossT,
    float* __restrict__ out)
{
  int g2 = blockIdx.z, gp2 = g2 >> 3, b = g2 & 7;
  const u16* S = (gp2 == 0) ? crossT + (long)b * kPLANE : gx2T + (long)g2 * kPLANE;
  __shared__ u16 t[32][33];
  int m0 = blockIdx.x * 32, c0 = blockIdx.y * 32;
  int tx = threadIdx.x, ty = threadIdx.y;
  for (int r = ty; r < 32; r += 8) t[r][tx] = S[(long)(m0 + r) * 512 + c0 + tx];
  __syncthreads();
  for (int r = ty; r < 32; r += 8)
    out[((long)b * 512 + c0 + r) * 4096 + gp2 * 1024 + m0 + tx] = bf2f(t[tx][r]);
}

extern "C" void kernel_launch(void* const* d_in, const int* in_sizes, int n_in,
                              void* d_out, int out_size, void* d_ws, size_t ws_size,
                              hipStream_t stream)
{
  const float* feat = (const float*)d_in[0];
  const float* tg1 = (const float*)d_in[4];  const float* tb1 = (const float*)d_in[5];
  const float* tf1b = (const float*)d_in[7];
  const float* tf2b = (const float*)d_in[9];
  const float* tg2 = (const float*)d_in[10]; const float* tb2 = (const float*)d_in[11];
  const float* cg1 = (const float*)d_in[16]; const float* cb1 = (const float*)d_in[17];
  const float* cf1b = (const float*)d_in[19];
  const float* cf2b = (const float*)d_in[21];
  const float* cg2 = (const float*)d_in[22]; const float* cb2 = (const float*)d_in[23];

  // ---- ws layout (peak 112 MiB) ----
  char* wsb = (char*)d_ws;
  u16* WP = (u16*)wsb;                 // 7 proj weights (d,c) bf16: 3.5 MiB
  u16* WF = (u16*)(wsb + 4 * MB);      // 4 FFN weights bf16: 8 MiB
  float* SM = (float*)(wsb + 12 * MB); // fp32 smalls
  float* QG = SM;                      // 32*512
  float* SC = SM + 16384;              // 32*1024
  float* AL = SM + 49152;              // 32*1024
  float* KS = SM + 81920;              // 32*512
  float* Zb = SM + 98304;              // 32*1024
  float* ZR = SM + 131072;             // 24*1024
  float* YB = SM + 155648;             // 1024*512 fp32
  u16* P2 = (u16*)(wsb + 16 * MB);     // 32 planes
  u16* P3 = (u16*)(wsb + 48 * MB);     // 32 planes
  u16* P4 = (u16*)(wsb + 80 * MB);     // 32 planes (ends 112 MiB)

  // ---- d_out (64 MiB) doubles as scratch until final assemble ----
  char* ob = (char*)d_out;
  u16* KV  = (u16*)ob;                 // SA kvT: 16 MiB
  u16* GXT = (u16*)(ob + 16 * MB);     // gxT: 32 MiB (dead after y GEMM)
  u16* HID = (u16*)ob;                 // FFN hidden chunk: 64 MiB (kv+gxT dead)
  u16* KV2 = (u16*)(ob + 32 * MB);     // cross kvT: 4 MiB
  u16* PHF = (u16*)(ob + 36 * MB);     // phi_first: 8 MiB
  u16* K0S = (u16*)(ob + 44 * MB);     // k0*alpha (c,n): 8 MiB
  u16* V0S = (u16*)(ob + 52 * MB);     // v0 (c,n): 8 MiB

  u16 *WPqk = WP,           *WPv  = WP + SZW,     *WPphi = WP + 2 * SZW,
      *WPcq = WP + 3 * SZW, *WPck = WP + 4 * SZW, *WPcv  = WP + 5 * SZW,
      *WPcphi = WP + 6 * SZW;
  u16 *WF1 = WF, *WF2 = WF + 1048576, *WF3 = WF + 2097152, *WF4 = WF + 3145728;

  dim3 b256(256), bT(32, 8);
  const float rsc = 1.0f / sqrtf(512.0f);
  const long PL = kPLANE;

  // 0. weight casts (no transposes needed in NT world)
  const float* wsrc[7] = {(const float*)d_in[1], (const float*)d_in[2], (const float*)d_in[3],
                          (const float*)d_in[12], (const float*)d_in[13], (const float*)d_in[14],
                          (const float*)d_in[15]};
  for (int i = 0; i < 7; ++i)
    castf2b<<<1024, b256, 0, stream>>>(wsrc[i], WP + i * SZW, 262144);
  castf2b<<<4096, b256, 0, stream>>>((const float*)d_in[6],  WF1, 1048576);
  castf2b<<<4096, b256, 0, stream>>>((const float*)d_in[8],  WF2, 1048576);
  castf2b<<<4096, b256, 0, stream>>>((const float*)d_in[18], WF3, 1048576);
  castf2b<<<4096, b256, 0, stream>>>((const float*)d_in[20], WF4, 1048576);

  // ---------------- SA block (all tensors (g,n,c) T-layout) ----------------
  gather_feat<<<dim3(32, 16, 8), bT, 0, stream>>>(feat, GXT);
  // qT = phi(gxT . Wqk^T)
  gemm_mfma<<<dim3(4, 8, 32), b256, 0, stream>>>(GXT, PL, 31, WPqk, 0, 0, P2, PL,
      1024, 512, 512, 1.f, 2, nullptr, nullptr, 0, nullptr, nullptr);
  colsum<<<dim3(2, 32), b256, 0, stream>>>(P2, PL, nullptr, QG, 1.f / 1024.f);
  rowdot<<<dim3(256, 32), b256, 0, stream>>>(P2, PL, QG, 31, SC, 0);
  softmax_row<<<32, b256, 0, stream>>>(SC, AL);
  // vT, then transpose v and k'=q*alpha into (c,n) layout for kv GEMM
  gemm_mfma<<<dim3(4, 8, 32), b256, 0, stream>>>(GXT, PL, 31, WPv, 0, 0, P3, PL,
      1024, 512, 512, 1.f, 0, nullptr, nullptr, 0, nullptr, nullptr);
  transpose_b<<<dim3(32, 16, 32), bT, 0, stream>>>(P3, P4, nullptr);  // v
  transpose_b<<<dim3(32, 16, 32), bT, 0, stream>>>(P2, P3, AL);       // k'
  // kvT[d][c] = sum_n v[d][n] k'[c][n] * rsc
  gemm_mfma<<<dim3(4, 4, 32), b256, 0, stream>>>(P4, PL, 31, P3, PL, 31, KV, SZW,
      512, 512, 1024, rsc, 0, nullptr, nullptr, 0, nullptr, nullptr);
  colsum<<<dim3(2, 32), b256, 0, stream>>>(P2, PL, AL, KS, 1.f);
  rowdot<<<dim3(256, 32), b256, 0, stream>>>(P2, PL, KS, 31, Zb, 1);
  // phixT
  gemm_mfma<<<dim3(4, 8, 32), b256, 0, stream>>>(GXT, PL, 31, WPphi, 0, 0, P4, PL,
      1024, 512, 512, 1.f, 0, nullptr, nullptr, 0, nullptr, nullptr);
  // h_preT = qT.kvT * z[n] * phixT + gxT
  gemm_mfma<<<dim3(4, 8, 32), b256, 0, stream>>>(P2, PL, 31, KV, SZW, 31, P3, PL,
      1024, 512, 512, 1.f, 0, nullptr, Zb, 1024, P4, GXT);
  ln_rows<<<32768, b256, 0, stream>>>(P3, tg1, tb1, P2, 0);
  // FFN 512->2048->512, 2 chunks of 16384 rows (HID = full 64 MiB d_out)
  for (int ch = 0; ch < 2; ++ch) {
    const u16* Hc = P2 + (long)ch * 16 * PL;
    gemm_mfma<<<dim3(16, 128, 1), b256, 0, stream>>>(Hc, 0, 0, WF1, 0, 0, HID, 0,
        16384, 2048, 512, 1.f, 1, tf1b, nullptr, 0, nullptr, nullptr);
    gemm_mfma<<<dim3(4, 128, 1), b256, 0, stream>>>(HID, 0, 0, WF2, 0, 0,
        P3 + (long)ch * 16 * PL, 0, 16384, 512, 2048, 1.f, 0, tf2b, nullptr, 0, nullptr, Hc);
  }
  ln_rows<<<32768, b256, 0, stream>>>(P3, tg2, tb2, P2, 1);       // t_saT
  gather_x2<<<32768, b256, 0, stream>>>(P2, P4);                  // gx2T

  // ---------------- cross block ----------------
  gemm_mfma<<<dim3(4, 8, 24), b256, 0, stream>>>(P4 + 8 * PL, PL, 31, WPcq, 0, 0, P2, PL,
      1024, 512, 512, 1.f, 2, nullptr, nullptr, 0, nullptr, nullptr);        // q_restT
  gemm_mfma<<<dim3(4, 8, 24), b256, 0, stream>>>(P4 + 8 * PL, PL, 31, WPcphi, 0, 0, P3, PL,
      1024, 512, 512, 1.f, 0, nullptr, nullptr, 0, nullptr, nullptr);        // phi_restT
  gemm_mfma<<<dim3(4, 8, 8), b256, 0, stream>>>(P4, PL, 31, WPck, 0, 0, P2 + 24 * PL, PL,
      1024, 512, 512, 1.f, 2, nullptr, nullptr, 0, nullptr, nullptr);        // k0T
  gemm_mfma<<<dim3(4, 8, 8), b256, 0, stream>>>(P4, PL, 31, WPcv, 0, 0, P3 + 24 * PL, PL,
      1024, 512, 512, 1.f, 0, nullptr, nullptr, 0, nullptr, nullptr);        // v0T
  gemm_mfma<<<dim3(4, 8, 8), b256, 0, stream>>>(P4, PL, 31, WPcphi, 0, 0, PHF, PL,
      1024, 512, 512, 1.f, 0, nullptr, nullptr, 0, nullptr, nullptr);        // phi_firstT
  colsum<<<dim3(2, 8), b256, 0, stream>>>(P2 + 24 * PL, PL, nullptr, QG, 1.f / 1024.f);
  rowdot<<<dim3(256, 8), b256, 0, stream>>>(P2 + 24 * PL, PL, QG, 7, SC, 0);
  softmax_row<<<8, b256, 0, stream>>>(SC, AL);
  transpose_b<<<dim3(32, 16, 8), bT, 0, stream>>>(P2 + 24 * PL, K0S, AL);  // k0'
  transpose_b<<<dim3(32, 16, 8), bT, 0, stream>>>(P3 + 24 * PL, V0S, nullptr);
  gemm_mfma<<<dim3(4, 4, 8), b256, 0, stream>>>(V0S, PL, 31, K0S, PL, 31, KV2, SZW,
      512, 512, 1024, rsc, 0, nullptr, nullptr, 0, nullptr, nullptr);
  colsum<<<dim3(2, 8), b256, 0, stream>>>(P2 + 24 * PL, PL, AL, KS, 1.f);
  rowdot<<<dim3(256, 24), b256, 0, stream>>>(P2, PL, KS, 7, ZR, 1);
  // y_restT = q_restT.kvT2[g&7] * z[n] * phi_restT  (in-place into P3)
  gemm_mfma<<<dim3(4, 8, 24), b256, 0, stream>>>(P2, PL, 31, KV2, SZW, 7, P3, PL,
      1024, 512, 512, 1.f, 0, nullptr, ZR, 1024, P3, nullptr);
  ybar_k<<<2048, b256, 0, stream>>>(P3, YB);
  hfirst_k<<<16384, b256, 0, stream>>>(P4, PHF, YB, P2 + 24 * PL);   // h_first
  ln_rows<<<8192, b256, 0, stream>>>(P2 + 24 * PL, cg1, cb1, P3 + 24 * PL, 0);
  gemm_mfma<<<dim3(16, 64, 1), b256, 0, stream>>>(P3 + 24 * PL, 0, 0, WF3, 0, 0, HID, 0,
      8192, 2048, 512, 1.f, 1, cf1b, nullptr, 0, nullptr, nullptr);
  gemm_mfma<<<dim3(4, 64, 1), b256, 0, stream>>>(HID, 0, 0, WF4, 0, 0, P2 + 24 * PL, 0,
      8192, 512, 2048, 1.f, 0, cf2b, nullptr, 0, nullptr, P3 + 24 * PL);
  ln_rows<<<8192, b256, 0, stream>>>(P2 + 24 * PL, cg2, cb2, P3 + 24 * PL, 1); // crossT
  assemble_t<<<dim3(32, 16, 32), bT, 0, stream>>>(P4, P3 + 24 * PL, (float*)d_out);
}

// Round 3
// 1220.667 us; speedup vs baseline: 1.0848x; 1.0660x over previous
//
#include <hip/hip_runtime.h>
#include <math.h>

using u16 = unsigned short;
typedef __attribute__((ext_vector_type(8))) short short8;
typedef __attribute__((ext_vector_type(4))) float f32x4;

// B=8, C=512, N=4096, GP=4 -> G=32 groups, NG=1024, F=2048
constexpr long kPLANE = 1024l * 512;     // elems per (g) plane, T-layout (n, c)
constexpr long SZW    = 512l * 512;
constexpr long MB     = 1l << 20;

__device__ __forceinline__ float bf2f(u16 u) {
  return __uint_as_float(((unsigned int)u) << 16);
}
__device__ __forceinline__ u16 f2bf(float f) {
  unsigned int x = __float_as_uint(f);
  x += 0x7fffu + ((x >> 16) & 1u);
  return (u16)(x >> 16);
}

// ---------------------------------------------------------------------------
// Unified MFMA GEMM (NT form): Out[g][m][n] = epi( scale * sum_k A[m][k]*B[n][k] )
// A (M x K) bf16 K-contig, B (N x K) bf16 K-contig. 128x128 tile, BK=32,
// 4 waves each 64x64 via 4x4 v_mfma_f32_16x16x32_bf16.
// Register staging, depth-2 prefetch, one barrier per K-step.
// + XCD-aware bijective block swizzle (each XCD gets a contiguous grid chunk
//   -> A-panel sharers land in one L2; FETCH ~4x lower).
// + LDS chunk XOR-swizzle: chunk c of row r placed at c^((r>>1)&3). Both
//   write (reg-staged) and fragment-read apply it -> ds_read_b128 lanes
//   spread 2-per-bank-group (free) instead of 8 (4 extra cyc/read).
// epi: *rowscale[g][m] -> *pmul[g][m][n] -> +bias[n] -> +resid[g][m][n] -> act
// act: 0 none, 1 relu, 2 relu+1 (phi). pmul may alias Out.
// ---------------------------------------------------------------------------
__global__ __launch_bounds__(256) void gemm_mfma(
    const u16* __restrict__ A, long sA, int amask,
    const u16* __restrict__ B, long sB, int bmask,
    u16* __restrict__ Out, long sO,
    int M, int Nn, int K, float scale, int act,
    const float* __restrict__ bias,
    const float* __restrict__ rowscale, long sRS,
    const u16* __restrict__ pmul, const u16* __restrict__ resid)
{
  // XCD-aware bijective remap (m204): linearize grid, chunk over 8 XCDs.
  int gx = gridDim.x, gy = gridDim.y;
  int nwg = gx * gy * gridDim.z;
  int lin = blockIdx.x + gx * (blockIdx.y + gy * blockIdx.z);
  int qq = nwg >> 3, rr = nwg & 7;
  int xcd = lin & 7, idx = lin >> 3;
  int wg = (xcd < rr ? xcd * (qq + 1) : rr * (qq + 1) + (xcd - rr) * qq) + idx;
  int bx = wg % gx; int t_ = wg / gx; int by = t_ % gy; int g = t_ / gy;

  const u16* Ag = A + (long)(g & amask) * sA;
  const u16* Bg = B + (long)(g & bmask) * sB;
  u16* Og = Out + (long)g * sO;
  int m0 = by * 128, n0 = bx * 128;

  __shared__ __align__(16) u16 As[2][128 * 32];
  __shared__ __align__(16) u16 Bs[2][128 * 32];

  int tid = threadIdx.x;
  int w = tid >> 6, L = tid & 63;
  int wm = (w >> 1) * 64, wn = (w & 1) * 64;
  int l15 = L & 15, l4 = L >> 4;

  f32x4 acc[4][4] = {};

  // staging: 512 16B-chunks per 128x32 tile; thread covers chunks tid, tid+256.
  // LDS slot: row r keeps its 64B but its four 16B chunks are permuted by
  // c' = c ^ ((r>>1)&3). For r0=tid>>2: (r0>>1)&3 == (tid>>3)&3; r1=r0+64 has
  // the same xor (64>>1=32, &3=0).
  int r0 = tid >> 2, r1 = r0 + 64;
  int kk = (tid & 3) * 8;
  int cxor = (tid >> 3) & 3;
  int s0 = r0 * 32 + (((tid & 3) ^ cxor) << 3);
  int s1 = s0 + 64 * 32;
  const u16* gA0 = Ag + (long)(m0 + r0) * K + kk;
  const u16* gA1 = Ag + (long)(m0 + r1) * K + kk;
  const u16* gB0 = Bg + (long)(n0 + r0) * K + kk;
  const u16* gB1 = Bg + (long)(n0 + r1) * K + kk;

  // fragment-read column with matching swizzle: row = wm+mi*16+l15 ->
  // (row>>1)&3 == (l15>>1)&3 (wm,mi*16 contribute 0 mod 4 after >>1).
  int rcol = (l4 << 3) ^ (((l15 >> 1) & 3) << 3);

  int nsteps = K >> 5;   // K in {512,1024,2048} -> nsteps even, >= 16

  // reg set P (pa*) and set Q (qa*)
  short8 pa0, pa1, pb0, pb1, qa0, qa1, qb0, qb1;

  // prologue: tile0 -> setP -> LDS[0]; issue tile1 -> setQ
  pa0 = *(const short8*)gA0; pa1 = *(const short8*)gA1;
  pb0 = *(const short8*)gB0; pb1 = *(const short8*)gB1;
  *(short8*)&As[0][s0] = pa0; *(short8*)&As[0][s1] = pa1;
  *(short8*)&Bs[0][s0] = pb0; *(short8*)&Bs[0][s1] = pb1;
  qa0 = *(const short8*)(gA0 + 32); qa1 = *(const short8*)(gA1 + 32);
  qb0 = *(const short8*)(gB0 + 32); qb1 = *(const short8*)(gB1 + 32);
  __syncthreads();

  // step KS: consume LDS[CUR]; HOLD_* holds tile KS+1 (write to LDS[NXT]);
  // issue tile KS+2 into OTH_* (the set whose data was written last step).
#define GSTEP(KS, CUR, NXT, HA0, HA1, HB0, HB1, OA0, OA1, OB0, OB1)            \
  {                                                                            \
    if ((KS) + 2 < nsteps) {                                                   \
      int ko = ((KS) + 2) << 5;                                                \
      OA0 = *(const short8*)(gA0 + ko); OA1 = *(const short8*)(gA1 + ko);      \
      OB0 = *(const short8*)(gB0 + ko); OB1 = *(const short8*)(gB1 + ko);      \
    }                                                                          \
    short8 af[4], bf[4];                                                       \
    _Pragma("unroll") for (int mi = 0; mi < 4; ++mi)                           \
      af[mi] = *(const short8*)&As[CUR][(wm + mi * 16 + l15) * 32 + rcol];     \
    _Pragma("unroll") for (int ni = 0; ni < 4; ++ni)                           \
      bf[ni] = *(const short8*)&Bs[CUR][(wn + ni * 16 + l15) * 32 + rcol];     \
    _Pragma("unroll") for (int mi = 0; mi < 4; ++mi)                           \
      _Pragma("unroll") for (int ni = 0; ni < 4; ++ni)                         \
        acc[mi][ni] = __builtin_amdgcn_mfma_f32_16x16x32_bf16(                 \
            bf[ni], af[mi], acc[mi][ni], 0, 0, 0);                             \
    if ((KS) + 1 < nsteps) {                                                   \
      *(short8*)&As[NXT][s0] = HA0; *(short8*)&As[NXT][s1] = HA1;              \
      *(short8*)&Bs[NXT][s0] = HB0; *(short8*)&Bs[NXT][s1] = HB1;              \
    }                                                                          \
    __syncthreads();                                                           \
  }

  for (int ks = 0; ks < nsteps; ks += 2) {
    GSTEP(ks,     0, 1, qa0, qa1, qb0, qb1, pa0, pa1, pb0, pb1)  // setQ=ks+1
    GSTEP(ks + 1, 1, 0, pa0, pa1, pb0, pb1, qa0, qa1, qb0, qb1)  // setP=ks+2
  }
#undef GSTEP

  // epilogue (operand-swapped D): lane holds n = nb..nb+3 at fixed m
  //   m = m0+wm+mi*16+l15 ; nb = n0+wn+ni*16+l4*4
#pragma unroll
  for (int mi = 0; mi < 4; ++mi) {
    int m = m0 + wm + mi * 16 + l15;
    float rs = rowscale ? rowscale[(long)g * sRS + m] : 1.f;
    float srs = scale * rs;
#pragma unroll
    for (int ni = 0; ni < 4; ++ni) {
      int nb = n0 + wn + ni * 16 + l4 * 4;
      long off = (long)m * Nn + nb;
      float v[4];
#pragma unroll
      for (int r = 0; r < 4; ++r) v[r] = acc[mi][ni][r] * srs;
      if (pmul) {
        ushort4 pm = *(const ushort4*)&pmul[(long)g * sO + off];
        v[0] *= bf2f(pm.x); v[1] *= bf2f(pm.y); v[2] *= bf2f(pm.z); v[3] *= bf2f(pm.w);
      }
      if (bias) {
        float4 bi = *(const float4*)&bias[nb];
        v[0] += bi.x; v[1] += bi.y; v[2] += bi.z; v[3] += bi.w;
      }
      if (resid) {
        ushort4 rd = *(const ushort4*)&resid[(long)g * sO + off];
        v[0] += bf2f(rd.x); v[1] += bf2f(rd.y); v[2] += bf2f(rd.z); v[3] += bf2f(rd.w);
      }
      if (act == 1) {
#pragma unroll
        for (int r = 0; r < 4; ++r) v[r] = fmaxf(v[r], 0.f);
      } else if (act == 2) {
#pragma unroll
        for (int r = 0; r < 4; ++r) v[r] = fmaxf(v[r], 0.f) + 1.f;
      }
      ushort4 o; o.x = f2bf(v[0]); o.y = f2bf(v[1]); o.z = f2bf(v[2]); o.w = f2bf(v[3]);
      *(ushort4*)&Og[off] = o;
    }
  }
}

// fp32 -> bf16 batched casts: 7 proj weights (262144 each) in one launch
__global__ __launch_bounds__(256) void cast7(
    const float* a0, const float* a1, const float* a2, const float* a3,
    const float* a4, const float* a5, const float* a6, u16* __restrict__ dst)
{
  int w = blockIdx.y;
  const float* s = w == 0 ? a0 : w == 1 ? a1 : w == 2 ? a2 : w == 3 ? a3
                 : w == 4 ? a4 : w == 5 ? a5 : a6;
  long i = (long)blockIdx.x * 256 + threadIdx.x;
  dst[(long)w * SZW + i] = f2bf(s[i]);
}

// 4 FFN weights (1048576 each) in one launch
__global__ __launch_bounds__(256) void cast4(
    const float* a0, const float* a1, const float* a2, const float* a3,
    u16* __restrict__ dst)
{
  int w = blockIdx.y;
  const float* s = w == 0 ? a0 : w == 1 ? a1 : w == 2 ? a2 : a3;
  long i = (long)blockIdx.x * 256 + threadIdx.x;
  dst[(long)w * 1048576 + i] = f2bf(s[i]);
}

// gxT[gp*8+b][n][c] = feat[b][c][4n+gp]  (fp32 -> bf16). grid(32,16,8) block(32,8)
__global__ __launch_bounds__(256) void gather_feat(
    const float* __restrict__ feat, u16* __restrict__ gxT)
{
  __shared__ float t[32][132];
  int b = blockIdx.z, c0 = blockIdx.y * 32, nf0 = blockIdx.x * 128;
  int tx = threadIdx.x, ty = threadIdx.y;
  for (int r = ty; r < 32; r += 8)
    *(float4*)&t[r][tx * 4] = *(const float4*)&feat[((long)b * 512 + c0 + r) * 4096 + nf0 + tx * 4];
  __syncthreads();
  int n0o = nf0 >> 2;
  for (int gp = 0; gp < 4; ++gp) {
    long gbase = (long)(gp * 8 + b) * kPLANE;
    for (int jr = ty; jr < 32; jr += 8)
      gxT[gbase + (long)(n0o + jr) * 512 + c0 + tx] = f2bf(t[tx][jr * 4 + gp]);
  }
}

// out[g][c][n] = in[g][n][c] * (alpha ? alpha[g][n] : 1). grid(32,16,G) block(32,8)
__global__ __launch_bounds__(256) void transpose_b(
    const u16* __restrict__ in, u16* __restrict__ out, const float* __restrict__ alpha)
{
  int g = blockIdx.z;
  const u16* I = in + (long)g * kPLANE;
  u16* O = out + (long)g * kPLANE;
  __shared__ u16 t[32][33];
  int n0 = blockIdx.x * 32, c0 = blockIdx.y * 32;
  int tx = threadIdx.x, ty = threadIdx.y;
  for (int r = ty; r < 32; r += 8) t[r][tx] = I[(long)(n0 + r) * 512 + c0 + tx];
  __syncthreads();
  float al = alpha ? alpha[(long)g * 1024 + n0 + tx] : 1.f;
  for (int r = ty; r < 32; r += 8)
    O[(long)(c0 + r) * 1024 + n0 + tx] = f2bf(bf2f(t[tx][r]) * al);
}

// out[g][c] = scale * sum_n X[g][n][c] * (alpha ? alpha[g][n] : 1). grid(2,G)
__global__ __launch_bounds__(256) void colsum(
    const u16* __restrict__ X, long sX, const float* __restrict__ alpha,
    float* __restrict__ out, float scale)
{
  int g = blockIdx.y;
  int c = blockIdx.x * 256 + threadIdx.x;
  const u16* Xg = X + (long)g * sX;
  float s = 0.f;
  for (int n = 0; n < 1024; ++n)
    s += bf2f(Xg[(long)n * 512 + c]) * (alpha ? alpha[(long)g * 1024 + n] : 1.f);
  out[(long)g * 512 + c] = s * scale;
}

// out[g][n] = f( sum_c X[g][n][c] * w[(g&wmask)][c] ). mode1: 1/(x+1e-6). grid(256,G)
__global__ __launch_bounds__(256) void rowdot(
    const u16* __restrict__ X, long sX, const float* __restrict__ w, int wmask,
    float* __restrict__ out, int mode)
{
  int g = blockIdx.y;
  int n = blockIdx.x * 4 + (threadIdx.x >> 6);
  int L = threadIdx.x & 63;
  const u16* row = X + (long)g * sX + (long)n * 512;
  short8 xv = *(const short8*)&row[L * 8];
  const float* wg = w + (long)(g & wmask) * 512;
  float4 w0 = *(const float4*)&wg[L * 8];
  float4 w1 = *(const float4*)&wg[L * 8 + 4];
  float s = bf2f((u16)xv[0]) * w0.x + bf2f((u16)xv[1]) * w0.y +
            bf2f((u16)xv[2]) * w0.z + bf2f((u16)xv[3]) * w0.w +
            bf2f((u16)xv[4]) * w1.x + bf2f((u16)xv[5]) * w1.y +
            bf2f((u16)xv[6]) * w1.z + bf2f((u16)xv[7]) * w1.w;
#pragma unroll
  for (int off = 32; off >= 1; off >>= 1) s += __shfl_down(s, off);
  if (L == 0) out[(long)g * 1024 + n] = mode ? 1.f / (s + 1e-6f) : s;
}

// alpha[g][n] = softmax_n(sc[g])[n] * 1024. grid(G)
__global__ __launch_bounds__(256) void softmax_row(
    const float* __restrict__ sc, float* __restrict__ out)
{
  int g = blockIdx.x, tid = threadIdx.x;
  const float* s = sc + (long)g * 1024;
  float* o = out + (long)g * 1024;
  __shared__ float red[256];
  float lm = -3.4e38f;
  for (int n = tid; n < 1024; n += 256) lm = fmaxf(lm, s[n]);
  red[tid] = lm; __syncthreads();
  for (int st = 128; st; st >>= 1) { if (tid < st) red[tid] = fmaxf(red[tid], red[tid + st]); __syncthreads(); }
  float mx = red[0]; __syncthreads();
  float ls = 0.f;
  for (int n = tid; n < 1024; n += 256) ls += __expf(s[n] - mx);
  red[tid] = ls; __syncthreads();
  for (int st = 128; st; st >>= 1) { if (tid < st) red[tid] += red[tid + st]; __syncthreads(); }
  float inv = 1024.f / red[0];
  for (int n = tid; n < 1024; n += 256) o[n] = __expf(s[n] - mx) * inv;
}

// LayerNorm over 512-wide contiguous rows, bf16 in/out, fp32 gamma/beta.
__global__ __launch_bounds__(256) void ln_rows(
    const u16* __restrict__ X, const float* __restrict__ gamma,
    const float* __restrict__ beta, u16* __restrict__ Out, int relu)
{
  long m = blockIdx.x;
  const u16* x = X + m * 512;
  u16* o = Out + m * 512;
  int tid = threadIdx.x;
  ushort2 u2 = *(const ushort2*)&x[tid * 2];
  float v0 = bf2f(u2.x), v1 = bf2f(u2.y);
  __shared__ float red[256];
  red[tid] = v0 + v1; __syncthreads();
  for (int st = 128; st; st >>= 1) { if (tid < st) red[tid] += red[tid + st]; __syncthreads(); }
  float mu = red[0] * (1.f / 512.f);
  __syncthreads();
  float d0 = v0 - mu, d1 = v1 - mu;
  red[tid] = d0 * d0 + d1 * d1; __syncthreads();
  for (int st = 128; st; st >>= 1) { if (tid < st) red[tid] += red[tid + st]; __syncthreads(); }
  float rs = rsqrtf(red[0] * (1.f / 512.f) + 1e-6f);
  float2 gm = *(const float2*)&gamma[tid * 2];
  float2 bt = *(const float2*)&beta[tid * 2];
  float o0 = d0 * rs * gm.x + bt.x, o1 = d1 * rs * gm.y + bt.y;
  if (relu) { o0 = fmaxf(o0, 0.f); o1 = fmaxf(o1, 0.f); }
  ushort2 r; r.x = f2bf(o0); r.y = f2bf(o1);
  *(ushort2*)&o[tid * 2] = r;
}

// Fused: Out[g2][m] = relu(LN(X[srcrow(g2,m)])) with the gather_x2 row map.
// Replaces ln_rows(tg2)+gather_x2 (saves one 64MB write + 64MB read). grid 32768
__global__ __launch_bounds__(256) void ln_gather(
    const u16* __restrict__ X, const float* __restrict__ gamma,
    const float* __restrict__ beta, u16* __restrict__ Out)
{
  int bid = blockIdx.x;
  int g2 = bid >> 10, m = bid & 1023;
  long src = ((long)((m & 3) * 8 + (g2 & 7)) * 1024 + (g2 >> 3) * 256 + (m >> 2)) * 512;
  const u16* x = X + src;
  u16* o = Out + (long)bid * 512;
  int tid = threadIdx.x;
  ushort2 u2 = *(const ushort2*)&x[tid * 2];
  float v0 = bf2f(u2.x), v1 = bf2f(u2.y);
  __shared__ float red[256];
  red[tid] = v0 + v1; __syncthreads();
  for (int st = 128; st; st >>= 1) { if (tid < st) red[tid] += red[tid + st]; __syncthreads(); }
  float mu = red[0] * (1.f / 512.f);
  __syncthreads();
  float d0 = v0 - mu, d1 = v1 - mu;
  red[tid] = d0 * d0 + d1 * d1; __syncthreads();
  for (int st = 128; st; st >>= 1) { if (tid < st) red[tid] += red[tid + st]; __syncthreads(); }
  float rs = rsqrtf(red[0] * (1.f / 512.f) + 1e-6f);
  float2 gm = *(const float2*)&gamma[tid * 2];
  float2 bt = *(const float2*)&beta[tid * 2];
  float o0 = fmaxf(d0 * rs * gm.x + bt.x, 0.f);
  float o1 = fmaxf(d1 * rs * gm.y + bt.y, 0.f);
  ushort2 r; r.x = f2bf(o0); r.y = f2bf(o1);
  *(ushort2*)&o[tid * 2] = r;
}

// ybar = mean over 24 planes (bf16 in, fp32 out). grid 2048
__global__ __launch_bounds__(256) void ybar_k(
    const u16* __restrict__ Y, float* __restrict__ yb)
{
  long idx = (long)blockIdx.x * 256 + threadIdx.x;
  float s = 0.f;
#pragma unroll
  for (int g = 0; g < 24; ++g) s += bf2f(Y[(long)g * kPLANE + idx]);
  yb[idx] = s * (1.f / 24.f);
}

// h_first[b][n][c] = gx2T[b][n][c] + ybar[n][c]*phiF[b][n][c]. grid 16384
__global__ __launch_bounds__(256) void hfirst_k(
    const u16* __restrict__ gx2, const u16* __restrict__ phiF,
    const float* __restrict__ yb, u16* __restrict__ h)
{
  long idx = (long)blockIdx.x * 256 + threadIdx.x;
  long p = idx & (kPLANE - 1);
  h[idx] = f2bf(bf2f(gx2[idx]) + yb[p] * bf2f(phiF[idx]));
}

// out[b][c][gp2*1024+m] = (gp2==0 ? crossT[b] : gx2T[g2])[m][c]. grid(32,16,32) block(32,8)
__global__ __launch_bounds__(256) void assemble_t(
    const u16* __restrict__ gx2T, const u16* __restrict__ crossT,
    float* __restrict__ out)
{
  int g2 = blockIdx.z, gp2 = g2 >> 3, b = g2 & 7;
  const u16* S = (gp2 == 0) ? crossT + (long)b * kPLANE : gx2T + (long)g2 * kPLANE;
  __shared__ u16 t[32][33];
  int m0 = blockIdx.x * 32, c0 = blockIdx.y * 32;
  int tx = threadIdx.x, ty = threadIdx.y;
  for (int r = ty; r < 32; r += 8) t[r][tx] = S[(long)(m0 + r) * 512 + c0 + tx];
  __syncthreads();
  for (int r = ty; r < 32; r += 8)
    out[((long)b * 512 + c0 + r) * 4096 + gp2 * 1024 + m0 + tx] = bf2f(t[tx][r]);
}

extern "C" void kernel_launch(void* const* d_in, const int* in_sizes, int n_in,
                              void* d_out, int out_size, void* d_ws, size_t ws_size,
                              hipStream_t stream)
{
  const float* feat = (const float*)d_in[0];
  const float* tg1 = (const float*)d_in[4];  const float* tb1 = (const float*)d_in[5];
  const float* tf1b = (const float*)d_in[7];
  const float* tf2b = (const float*)d_in[9];
  const float* tg2 = (const float*)d_in[10]; const float* tb2 = (const float*)d_in[11];
  const float* cg1 = (const float*)d_in[16]; const float* cb1 = (const float*)d_in[17];
  const float* cf1b = (const float*)d_in[19];
  const float* cf2b = (const float*)d_in[21];
  const float* cg2 = (const float*)d_in[22]; const float* cb2 = (const float*)d_in[23];

  // ---- ws layout (peak 112 MiB) ----
  char* wsb = (char*)d_ws;
  u16* WP = (u16*)wsb;                 // 7 proj weights (d,c) bf16: 3.5 MiB
  u16* WF = (u16*)(wsb + 4 * MB);      // 4 FFN weights bf16: 8 MiB
  float* SM = (float*)(wsb + 12 * MB); // fp32 smalls
  float* QG = SM;                      // 32*512
  float* SC = SM + 16384;              // 32*1024
  float* AL = SM + 49152;              // 32*1024
  float* KS = SM + 81920;              // 32*512
  float* Zb = SM + 98304;              // 32*1024
  float* ZR = SM + 131072;             // 24*1024
  float* YB = SM + 155648;             // 1024*512 fp32
  u16* P2 = (u16*)(wsb + 16 * MB);     // 32 planes
  u16* P3 = (u16*)(wsb + 48 * MB);     // 32 planes
  u16* P4 = (u16*)(wsb + 80 * MB);     // 32 planes (ends 112 MiB)

  // ---- d_out (64 MiB) doubles as scratch until final assemble ----
  char* ob = (char*)d_out;
  u16* KV  = (u16*)ob;                 // SA kvT: 16 MiB
  u16* GXT = (u16*)(ob + 16 * MB);     // gxT: 32 MiB (dead after y GEMM)
  u16* HID = (u16*)ob;                 // FFN hidden chunk: 64 MiB (kv+gxT dead)
  u16* KV2 = (u16*)(ob + 32 * MB);     // cross kvT: 4 MiB
  u16* PHF = (u16*)(ob + 36 * MB);     // phi_first: 8 MiB
  u16* K0S = (u16*)(ob + 44 * MB);     // k0*alpha (c,n): 8 MiB
  u16* V0S = (u16*)(ob + 52 * MB);     // v0 (c,n): 8 MiB

  u16 *WPqk = WP,           *WPv  = WP + SZW,     *WPphi = WP + 2 * SZW,
      *WPcq = WP + 3 * SZW, *WPck = WP + 4 * SZW, *WPcv  = WP + 5 * SZW,
      *WPcphi = WP + 6 * SZW;
  u16 *WF1 = WF, *WF2 = WF + 1048576, *WF3 = WF + 2097152, *WF4 = WF + 3145728;

  dim3 b256(256), bT(32, 8);
  const float rsc = 1.0f / sqrtf(512.0f);
  const long PL = kPLANE;

  // 0. weight casts, batched (no transposes needed in NT world)
  cast7<<<dim3(1024, 7), b256, 0, stream>>>(
      (const float*)d_in[1], (const float*)d_in[2], (const float*)d_in[3],
      (const float*)d_in[12], (const float*)d_in[13], (const float*)d_in[14],
      (const float*)d_in[15], WP);
  cast4<<<dim3(4096, 4), b256, 0, stream>>>(
      (const float*)d_in[6], (const float*)d_in[8],
      (const float*)d_in[18], (const float*)d_in[20], WF);

  // ---------------- SA block (all tensors (g,n,c) T-layout) ----------------
  gather_feat<<<dim3(32, 16, 8), bT, 0, stream>>>(feat, GXT);
  // qT = phi(gxT . Wqk^T)
  gemm_mfma<<<dim3(4, 8, 32), b256, 0, stream>>>(GXT, PL, 31, WPqk, 0, 0, P2, PL,
      1024, 512, 512, 1.f, 2, nullptr, nullptr, 0, nullptr, nullptr);
  colsum<<<dim3(2, 32), b256, 0, stream>>>(P2, PL, nullptr, QG, 1.f / 1024.f);
  rowdot<<<dim3(256, 32), b256, 0, stream>>>(P2, PL, QG, 31, SC, 0);
  softmax_row<<<32, b256, 0, stream>>>(SC, AL);
  // vT, then transpose v and k'=q*alpha into (c,n) layout for kv GEMM
  gemm_mfma<<<dim3(4, 8, 32), b256, 0, stream>>>(GXT, PL, 31, WPv, 0, 0, P3, PL,
      1024, 512, 512, 1.f, 0, nullptr, nullptr, 0, nullptr, nullptr);
  transpose_b<<<dim3(32, 16, 32), bT, 0, stream>>>(P3, P4, nullptr);  // v
  transpose_b<<<dim3(32, 16, 32), bT, 0, stream>>>(P2, P3, AL);       // k'
  // kvT[d][c] = sum_n v[d][n] k'[c][n] * rsc
  gemm_mfma<<<dim3(4, 4, 32), b256, 0, stream>>>(P4, PL, 31, P3, PL, 31, KV, SZW,
      512, 512, 1024, rsc, 0, nullptr, nullptr, 0, nullptr, nullptr);
  colsum<<<dim3(2, 32), b256, 0, stream>>>(P2, PL, AL, KS, 1.f);
  rowdot<<<dim3(256, 32), b256, 0, stream>>>(P2, PL, KS, 31, Zb, 1);
  // phixT
  gemm_mfma<<<dim3(4, 8, 32), b256, 0, stream>>>(GXT, PL, 31, WPphi, 0, 0, P4, PL,
      1024, 512, 512, 1.f, 0, nullptr, nullptr, 0, nullptr, nullptr);
  // h_preT = qT.kvT * z[n] * phixT + gxT
  gemm_mfma<<<dim3(4, 8, 32), b256, 0, stream>>>(P2, PL, 31, KV, SZW, 31, P3, PL,
      1024, 512, 512, 1.f, 0, nullptr, Zb, 1024, P4, GXT);
  ln_rows<<<32768, b256, 0, stream>>>(P3, tg1, tb1, P2, 0);
  // FFN 512->2048->512, 2 chunks of 16384 rows (HID = full 64 MiB d_out)
  for (int ch = 0; ch < 2; ++ch) {
    const u16* Hc = P2 + (long)ch * 16 * PL;
    gemm_mfma<<<dim3(16, 128, 1), b256, 0, stream>>>(Hc, 0, 0, WF1, 0, 0, HID, 0,
        16384, 2048, 512, 1.f, 1, tf1b, nullptr, 0, nullptr, nullptr);
    gemm_mfma<<<dim3(4, 128, 1), b256, 0, stream>>>(HID, 0, 0, WF2, 0, 0,
        P3 + (long)ch * 16 * PL, 0, 16384, 512, 2048, 1.f, 0, tf2b, nullptr, 0, nullptr, Hc);
  }
  ln_gather<<<32768, b256, 0, stream>>>(P3, tg2, tb2, P4);        // t_saT -> gx2T fused

  // ---------------- cross block ----------------
  gemm_mfma<<<dim3(4, 8, 24), b256, 0, stream>>>(P4 + 8 * PL, PL, 31, WPcq, 0, 0, P2, PL,
      1024, 512, 512, 1.f, 2, nullptr, nullptr, 0, nullptr, nullptr);        // q_restT
  gemm_mfma<<<dim3(4, 8, 24), b256, 0, stream>>>(P4 + 8 * PL, PL, 31, WPcphi, 0, 0, P3, PL,
      1024, 512, 512, 1.f, 0, nullptr, nullptr, 0, nullptr, nullptr);        // phi_restT
  gemm_mfma<<<dim3(4, 8, 8), b256, 0, stream>>>(P4, PL, 31, WPck, 0, 0, P2 + 24 * PL, PL,
      1024, 512, 512, 1.f, 2, nullptr, nullptr, 0, nullptr, nullptr);        // k0T
  gemm_mfma<<<dim3(4, 8, 8), b256, 0, stream>>>(P4, PL, 31, WPcv, 0, 0, P3 + 24 * PL, PL,
      1024, 512, 512, 1.f, 0, nullptr, nullptr, 0, nullptr, nullptr);        // v0T
  gemm_mfma<<<dim3(4, 8, 8), b256, 0, stream>>>(P4, PL, 31, WPcphi, 0, 0, PHF, PL,
      1024, 512, 512, 1.f, 0, nullptr, nullptr, 0, nullptr, nullptr);        // phi_firstT
  colsum<<<dim3(2, 8), b256, 0, stream>>>(P2 + 24 * PL, PL, nullptr, QG, 1.f / 1024.f);
  rowdot<<<dim3(256, 8), b256, 0, stream>>>(P2 + 24 * PL, PL, QG, 7, SC, 0);
  softmax_row<<<8, b256, 0, stream>>>(SC, AL);
  transpose_b<<<dim3(32, 16, 8), bT, 0, stream>>>(P2 + 24 * PL, K0S, AL);  // k0'
  transpose_b<<<dim3(32, 16, 8), bT, 0, stream>>>(P3 + 24 * PL, V0S, nullptr);
  gemm_mfma<<<dim3(4, 4, 8), b256, 0, stream>>>(V0S, PL, 31, K0S, PL, 31, KV2, SZW,
      512, 512, 1024, rsc, 0, nullptr, nullptr, 0, nullptr, nullptr);
  colsum<<<dim3(2, 8), b256, 0, stream>>>(P2 + 24 * PL, PL, AL, KS, 1.f);
  rowdot<<<dim3(256, 24), b256, 0, stream>>>(P2, PL, KS, 7, ZR, 1);
  // y_restT = q_restT.kvT2[g&7] * z[n] * phi_restT  (in-place into P3)
  gemm_mfma<<<dim3(4, 8, 24), b256, 0, stream>>>(P2, PL, 31, KV2, SZW, 7, P3, PL,
      1024, 512, 512, 1.f, 0, nullptr, ZR, 1024, P3, nullptr);
  ybar_k<<<2048, b256, 0, stream>>>(P3, YB);
  hfirst_k<<<16384, b256, 0, stream>>>(P4, PHF, YB, P2 + 24 * PL);   // h_first
  ln_rows<<<8192, b256, 0, stream>>>(P2 + 24 * PL, cg1, cb1, P3 + 24 * PL, 0);
  gemm_mfma<<<dim3(16, 64, 1), b256, 0, stream>>>(P3 + 24 * PL, 0, 0, WF3, 0, 0, HID, 0,
      8192, 2048, 512, 1.f, 1, cf1b, nullptr, 0, nullptr, nullptr);
  gemm_mfma<<<dim3(4, 64, 1), b256, 0, stream>>>(HID, 0, 0, WF4, 0, 0, P2 + 24 * PL, 0,
      8192, 512, 2048, 1.f, 0, cf2b, nullptr, 0, nullptr, P3 + 24 * PL);
  ln_rows<<<8192, b256, 0, stream>>>(P2 + 24 * PL, cg2, cb2, P3 + 24 * PL, 1); // crossT
  assemble_t<<<dim3(32, 16, 32), bT, 0, stream>>>(P4, P3 + 24 * PL, (float*)d_out);
}

// Round 4
// 1184.566 us; speedup vs baseline: 1.1178x; 1.0305x over previous
//
#include <hip/hip_runtime.h>
#include <math.h>

using u16 = unsigned short;
typedef __attribute__((ext_vector_type(8))) short short8;
typedef __attribute__((ext_vector_type(4))) float f32x4;

// B=8, C=512, N=4096, GP=4 -> G=32 groups, NG=1024, F=2048
constexpr long kPLANE = 1024l * 512;     // elems per (g) plane, T-layout (n, c)
constexpr long SZW    = 512l * 512;
constexpr long MB     = 1l << 20;

__device__ __forceinline__ float bf2f(u16 u) {
  return __uint_as_float(((unsigned int)u) << 16);
}
__device__ __forceinline__ u16 f2bf(float f) {
  unsigned int x = __float_as_uint(f);
  x += 0x7fffu + ((x >> 16) & 1u);
  return (u16)(x >> 16);
}

// ---------------------------------------------------------------------------
// Unified MFMA GEMM (NT form): Out[g][m][n] = epi( scale * sum_k A[m][k]*B[n][k] )
// A (M x K) bf16 K-contig, B (N x K) bf16 K-contig. 128x128 tile, BK=32,
// 4 waves each 64x64 via 4x4 v_mfma_f32_16x16x32_bf16.
// Register staging, depth-1 prefetch, one barrier per K-step.
// __launch_bounds__(256,4): cap 128 unified regs/wave (acc=64 AGPR + ~62
// arch) -> 4 blocks/CU resident (was 2 at ~140 regs) to hide the per-step
// barrier/ds_read chain latency across independent blocks.
// + XCD-aware bijective block swizzle (A-panel sharers in one L2).
// + LDS chunk XOR-swizzle (both-sides): bank-conflict-free ds_read_b128.
// epi: *rowscale[g][m] -> *pmul[g][m][n] -> +bias[n] -> +resid[g][m][n] -> act
// act: 0 none, 1 relu, 2 relu+1 (phi). pmul may alias Out.
// ---------------------------------------------------------------------------
__global__ __launch_bounds__(256, 4) void gemm_mfma(
    const u16* __restrict__ A, long sA, int amask,
    const u16* __restrict__ B, long sB, int bmask,
    u16* __restrict__ Out, long sO,
    int M, int Nn, int K, float scale, int act,
    const float* __restrict__ bias,
    const float* __restrict__ rowscale, long sRS,
    const u16* __restrict__ pmul, const u16* __restrict__ resid)
{
  // XCD-aware bijective remap (m204): linearize grid, chunk over 8 XCDs.
  int gx = gridDim.x, gy = gridDim.y;
  int nwg = gx * gy * gridDim.z;
  int lin = blockIdx.x + gx * (blockIdx.y + gy * blockIdx.z);
  int qq = nwg >> 3, rr = nwg & 7;
  int xcd = lin & 7, idx = lin >> 3;
  int wg = (xcd < rr ? xcd * (qq + 1) : rr * (qq + 1) + (xcd - rr) * qq) + idx;
  int bx = wg % gx; int t_ = wg / gx; int by = t_ % gy; int g = t_ / gy;

  const u16* Ag = A + (long)(g & amask) * sA;
  const u16* Bg = B + (long)(g & bmask) * sB;
  u16* Og = Out + (long)g * sO;
  int m0 = by * 128, n0 = bx * 128;

  __shared__ __align__(16) u16 As[2][128 * 32];
  __shared__ __align__(16) u16 Bs[2][128 * 32];

  int tid = threadIdx.x;
  int w = tid >> 6, L = tid & 63;
  int wm = (w >> 1) * 64, wn = (w & 1) * 64;
  int l15 = L & 15, l4 = L >> 4;

  f32x4 acc[4][4] = {};

  // staging: 512 16B-chunks per 128x32 tile; thread covers chunks tid, tid+256.
  // LDS slot: row r keeps its 64B but its four 16B chunks are permuted by
  // c' = c ^ ((r>>1)&3). For r0=tid>>2: (r0>>1)&3 == (tid>>3)&3; r1=r0+64 has
  // the same xor (64>>1=32, &3=0).
  int r0 = tid >> 2, r1 = r0 + 64;
  int kk = (tid & 3) * 8;
  int cxor = (tid >> 3) & 3;
  int s0 = r0 * 32 + (((tid & 3) ^ cxor) << 3);
  int s1 = s0 + 64 * 32;
  const u16* gA0 = Ag + (long)(m0 + r0) * K + kk;
  const u16* gA1 = Ag + (long)(m0 + r1) * K + kk;
  const u16* gB0 = Bg + (long)(n0 + r0) * K + kk;
  const u16* gB1 = Bg + (long)(n0 + r1) * K + kk;

  // fragment-read column with matching swizzle: row = wm+mi*16+l15 ->
  // (row>>1)&3 == (l15>>1)&3 (wm,mi*16 contribute 0 mod 4 after >>1).
  int rcol = (l4 << 3) ^ (((l15 >> 1) & 3) << 3);

  // preload tile 0 into LDS buffer 0
  short8 ra0 = *(const short8*)gA0;
  short8 ra1 = *(const short8*)gA1;
  short8 rb0 = *(const short8*)gB0;
  short8 rb1 = *(const short8*)gB1;
  *(short8*)&As[0][s0] = ra0; *(short8*)&As[0][s1] = ra1;
  *(short8*)&Bs[0][s0] = rb0; *(short8*)&Bs[0][s1] = rb1;
  __syncthreads();

  int nsteps = K >> 5;
  for (int ks = 0; ks < nsteps; ++ks) {
    int cur = ks & 1;
    if (ks + 1 < nsteps) {             // prefetch next K-tile into registers
      int ko = (ks + 1) << 5;
      ra0 = *(const short8*)(gA0 + ko);
      ra1 = *(const short8*)(gA1 + ko);
      rb0 = *(const short8*)(gB0 + ko);
      rb1 = *(const short8*)(gB1 + ko);
    }
    short8 af[4], bf[4];
#pragma unroll
    for (int mi = 0; mi < 4; ++mi)
      af[mi] = *(const short8*)&As[cur][(wm + mi * 16 + l15) * 32 + rcol];
#pragma unroll
    for (int ni = 0; ni < 4; ++ni)
      bf[ni] = *(const short8*)&Bs[cur][(wn + ni * 16 + l15) * 32 + rcol];
#pragma unroll
    for (int mi = 0; mi < 4; ++mi)
#pragma unroll
      for (int ni = 0; ni < 4; ++ni)
        acc[mi][ni] = __builtin_amdgcn_mfma_f32_16x16x32_bf16(bf[ni], af[mi], acc[mi][ni], 0, 0, 0);
    if (ks + 1 < nsteps) {             // write prefetched tile to other buffer
      int nxt = cur ^ 1;
      *(short8*)&As[nxt][s0] = ra0; *(short8*)&As[nxt][s1] = ra1;
      *(short8*)&Bs[nxt][s0] = rb0; *(short8*)&Bs[nxt][s1] = rb1;
    }
    __syncthreads();
  }

  // epilogue (operand-swapped D): lane holds n = nb..nb+3 at fixed m
  //   m = m0+wm+mi*16+l15 ; nb = n0+wn+ni*16+l4*4
#pragma unroll
  for (int mi = 0; mi < 4; ++mi) {
    int m = m0 + wm + mi * 16 + l15;
    float rs = rowscale ? rowscale[(long)g * sRS + m] : 1.f;
    float srs = scale * rs;
#pragma unroll
    for (int ni = 0; ni < 4; ++ni) {
      int nb = n0 + wn + ni * 16 + l4 * 4;
      long off = (long)m * Nn + nb;
      float v[4];
#pragma unroll
      for (int r = 0; r < 4; ++r) v[r] = acc[mi][ni][r] * srs;
      if (pmul) {
        ushort4 pm = *(const ushort4*)&pmul[(long)g * sO + off];
        v[0] *= bf2f(pm.x); v[1] *= bf2f(pm.y); v[2] *= bf2f(pm.z); v[3] *= bf2f(pm.w);
      }
      if (bias) {
        float4 bi = *(const float4*)&bias[nb];
        v[0] += bi.x; v[1] += bi.y; v[2] += bi.z; v[3] += bi.w;
      }
      if (resid) {
        ushort4 rd = *(const ushort4*)&resid[(long)g * sO + off];
        v[0] += bf2f(rd.x); v[1] += bf2f(rd.y); v[2] += bf2f(rd.z); v[3] += bf2f(rd.w);
      }
      if (act == 1) {
#pragma unroll
        for (int r = 0; r < 4; ++r) v[r] = fmaxf(v[r], 0.f);
      } else if (act == 2) {
#pragma unroll
        for (int r = 0; r < 4; ++r) v[r] = fmaxf(v[r], 0.f) + 1.f;
      }
      ushort4 o; o.x = f2bf(v[0]); o.y = f2bf(v[1]); o.z = f2bf(v[2]); o.w = f2bf(v[3]);
      *(ushort4*)&Og[off] = o;
    }
  }
}

// fp32 -> bf16 batched casts: 7 proj weights (262144 each) in one launch
__global__ __launch_bounds__(256) void cast7(
    const float* a0, const float* a1, const float* a2, const float* a3,
    const float* a4, const float* a5, const float* a6, u16* __restrict__ dst)
{
  int w = blockIdx.y;
  const float* s = w == 0 ? a0 : w == 1 ? a1 : w == 2 ? a2 : w == 3 ? a3
                 : w == 4 ? a4 : w == 5 ? a5 : a6;
  long i = (long)blockIdx.x * 256 + threadIdx.x;
  dst[(long)w * SZW + i] = f2bf(s[i]);
}

// 4 FFN weights (1048576 each) in one launch
__global__ __launch_bounds__(256) void cast4(
    const float* a0, const float* a1, const float* a2, const float* a3,
    u16* __restrict__ dst)
{
  int w = blockIdx.y;
  const float* s = w == 0 ? a0 : w == 1 ? a1 : w == 2 ? a2 : a3;
  long i = (long)blockIdx.x * 256 + threadIdx.x;
  dst[(long)w * 1048576 + i] = f2bf(s[i]);
}

// gxT[gp*8+b][n][c] = feat[b][c][4n+gp]  (fp32 -> bf16). grid(32,16,8) block(32,8)
__global__ __launch_bounds__(256) void gather_feat(
    const float* __restrict__ feat, u16* __restrict__ gxT)
{
  __shared__ float t[32][132];
  int b = blockIdx.z, c0 = blockIdx.y * 32, nf0 = blockIdx.x * 128;
  int tx = threadIdx.x, ty = threadIdx.y;
  for (int r = ty; r < 32; r += 8)
    *(float4*)&t[r][tx * 4] = *(const float4*)&feat[((long)b * 512 + c0 + r) * 4096 + nf0 + tx * 4];
  __syncthreads();
  int n0o = nf0 >> 2;
  for (int gp = 0; gp < 4; ++gp) {
    long gbase = (long)(gp * 8 + b) * kPLANE;
    for (int jr = ty; jr < 32; jr += 8)
      gxT[gbase + (long)(n0o + jr) * 512 + c0 + tx] = f2bf(t[tx][jr * 4 + gp]);
  }
}

// out[g][c][n] = in[g][n][c] * (alpha ? alpha[g][n] : 1). grid(32,16,G) block(32,8)
__global__ __launch_bounds__(256) void transpose_b(
    const u16* __restrict__ in, u16* __restrict__ out, const float* __restrict__ alpha)
{
  int g = blockIdx.z;
  const u16* I = in + (long)g * kPLANE;
  u16* O = out + (long)g * kPLANE;
  __shared__ u16 t[32][33];
  int n0 = blockIdx.x * 32, c0 = blockIdx.y * 32;
  int tx = threadIdx.x, ty = threadIdx.y;
  for (int r = ty; r < 32; r += 8) t[r][tx] = I[(long)(n0 + r) * 512 + c0 + tx];
  __syncthreads();
  float al = alpha ? alpha[(long)g * 1024 + n0 + tx] : 1.f;
  for (int r = ty; r < 32; r += 8)
    O[(long)(c0 + r) * 1024 + n0 + tx] = f2bf(bf2f(t[tx][r]) * al);
}

// out[g][c] = scale * sum_n X[g][n][c] * (alpha ? alpha[g][n] : 1). grid(2,G)
__global__ __launch_bounds__(256) void colsum(
    const u16* __restrict__ X, long sX, const float* __restrict__ alpha,
    float* __restrict__ out, float scale)
{
  int g = blockIdx.y;
  int c = blockIdx.x * 256 + threadIdx.x;
  const u16* Xg = X + (long)g * sX;
  float s = 0.f;
  for (int n = 0; n < 1024; ++n)
    s += bf2f(Xg[(long)n * 512 + c]) * (alpha ? alpha[(long)g * 1024 + n] : 1.f);
  out[(long)g * 512 + c] = s * scale;
}

// out[g][n] = f( sum_c X[g][n][c] * w[(g&wmask)][c] ). mode1: 1/(x+1e-6). grid(256,G)
__global__ __launch_bounds__(256) void rowdot(
    const u16* __restrict__ X, long sX, const float* __restrict__ w, int wmask,
    float* __restrict__ out, int mode)
{
  int g = blockIdx.y;
  int n = blockIdx.x * 4 + (threadIdx.x >> 6);
  int L = threadIdx.x & 63;
  const u16* row = X + (long)g * sX + (long)n * 512;
  short8 xv = *(const short8*)&row[L * 8];
  const float* wg = w + (long)(g & wmask) * 512;
  float4 w0 = *(const float4*)&wg[L * 8];
  float4 w1 = *(const float4*)&wg[L * 8 + 4];
  float s = bf2f((u16)xv[0]) * w0.x + bf2f((u16)xv[1]) * w0.y +
            bf2f((u16)xv[2]) * w0.z + bf2f((u16)xv[3]) * w0.w +
            bf2f((u16)xv[4]) * w1.x + bf2f((u16)xv[5]) * w1.y +
            bf2f((u16)xv[6]) * w1.z + bf2f((u16)xv[7]) * w1.w;
#pragma unroll
  for (int off = 32; off >= 1; off >>= 1) s += __shfl_down(s, off);
  if (L == 0) out[(long)g * 1024 + n] = mode ? 1.f / (s + 1e-6f) : s;
}

// alpha[g][n] = softmax_n(sc[g])[n] * 1024. grid(G)
__global__ __launch_bounds__(256) void softmax_row(
    const float* __restrict__ sc, float* __restrict__ out)
{
  int g = blockIdx.x, tid = threadIdx.x;
  const float* s = sc + (long)g * 1024;
  float* o = out + (long)g * 1024;
  __shared__ float red[256];
  float lm = -3.4e38f;
  for (int n = tid; n < 1024; n += 256) lm = fmaxf(lm, s[n]);
  red[tid] = lm; __syncthreads();
  for (int st = 128; st; st >>= 1) { if (tid < st) red[tid] = fmaxf(red[tid], red[tid + st]); __syncthreads(); }
  float mx = red[0]; __syncthreads();
  float ls = 0.f;
  for (int n = tid; n < 1024; n += 256) ls += __expf(s[n] - mx);
  red[tid] = ls; __syncthreads();
  for (int st = 128; st; st >>= 1) { if (tid < st) red[tid] += red[tid + st]; __syncthreads(); }
  float inv = 1024.f / red[0];
  for (int n = tid; n < 1024; n += 256) o[n] = __expf(s[n] - mx) * inv;
}

// LayerNorm over 512-wide contiguous rows, bf16 in/out, fp32 gamma/beta.
__global__ __launch_bounds__(256) void ln_rows(
    const u16* __restrict__ X, const float* __restrict__ gamma,
    const float* __restrict__ beta, u16* __restrict__ Out, int relu)
{
  long m = blockIdx.x;
  const u16* x = X + m * 512;
  u16* o = Out + m * 512;
  int tid = threadIdx.x;
  ushort2 u2 = *(const ushort2*)&x[tid * 2];
  float v0 = bf2f(u2.x), v1 = bf2f(u2.y);
  __shared__ float red[256];
  red[tid] = v0 + v1; __syncthreads();
  for (int st = 128; st; st >>= 1) { if (tid < st) red[tid] += red[tid + st]; __syncthreads(); }
  float mu = red[0] * (1.f / 512.f);
  __syncthreads();
  float d0 = v0 - mu, d1 = v1 - mu;
  red[tid] = d0 * d0 + d1 * d1; __syncthreads();
  for (int st = 128; st; st >>= 1) { if (tid < st) red[tid] += red[tid + st]; __syncthreads(); }
  float rs = rsqrtf(red[0] * (1.f / 512.f) + 1e-6f);
  float2 gm = *(const float2*)&gamma[tid * 2];
  float2 bt = *(const float2*)&beta[tid * 2];
  float o0 = d0 * rs * gm.x + bt.x, o1 = d1 * rs * gm.y + bt.y;
  if (relu) { o0 = fmaxf(o0, 0.f); o1 = fmaxf(o1, 0.f); }
  ushort2 r; r.x = f2bf(o0); r.y = f2bf(o1);
  *(ushort2*)&o[tid * 2] = r;
}

// Fused: Out[g2][m] = relu(LN(X[srcrow(g2,m)])) with the gather_x2 row map.
// Replaces ln_rows(tg2)+gather_x2 (saves one 64MB write + 64MB read). grid 32768
__global__ __launch_bounds__(256) void ln_gather(
    const u16* __restrict__ X, const float* __restrict__ gamma,
    const float* __restrict__ beta, u16* __restrict__ Out)
{
  int bid = blockIdx.x;
  int g2 = bid >> 10, m = bid & 1023;
  long src = ((long)((m & 3) * 8 + (g2 & 7)) * 1024 + (g2 >> 3) * 256 + (m >> 2)) * 512;
  const u16* x = X + src;
  u16* o = Out + (long)bid * 512;
  int tid = threadIdx.x;
  ushort2 u2 = *(const ushort2*)&x[tid * 2];
  float v0 = bf2f(u2.x), v1 = bf2f(u2.y);
  __shared__ float red[256];
  red[tid] = v0 + v1; __syncthreads();
  for (int st = 128; st; st >>= 1) { if (tid < st) red[tid] += red[tid + st]; __syncthreads(); }
  float mu = red[0] * (1.f / 512.f);
  __syncthreads();
  float d0 = v0 - mu, d1 = v1 - mu;
  red[tid] = d0 * d0 + d1 * d1; __syncthreads();
  for (int st = 128; st; st >>= 1) { if (tid < st) red[tid] += red[tid + st]; __syncthreads(); }
  float rs = rsqrtf(red[0] * (1.f / 512.f) + 1e-6f);
  float2 gm = *(const float2*)&gamma[tid * 2];
  float2 bt = *(const float2*)&beta[tid * 2];
  float o0 = fmaxf(d0 * rs * gm.x + bt.x, 0.f);
  float o1 = fmaxf(d1 * rs * gm.y + bt.y, 0.f);
  ushort2 r; r.x = f2bf(o0); r.y = f2bf(o1);
  *(ushort2*)&o[tid * 2] = r;
}

// ybar = mean over 24 planes (bf16 in, fp32 out). grid 2048
__global__ __launch_bounds__(256) void ybar_k(
    const u16* __restrict__ Y, float* __restrict__ yb)
{
  long idx = (long)blockIdx.x * 256 + threadIdx.x;
  float s = 0.f;
#pragma unroll
  for (int g = 0; g < 24; ++g) s += bf2f(Y[(long)g * kPLANE + idx]);
  yb[idx] = s * (1.f / 24.f);
}

// h_first[b][n][c] = gx2T[b][n][c] + ybar[n][c]*phiF[b][n][c]. grid 16384
__global__ __launch_bounds__(256) void hfirst_k(
    const u16* __restrict__ gx2, const u16* __restrict__ phiF,
    const float* __restrict__ yb, u16* __restrict__ h)
{
  long idx = (long)blockIdx.x * 256 + threadIdx.x;
  long p = idx & (kPLANE - 1);
  h[idx] = f2bf(bf2f(gx2[idx]) + yb[p] * bf2f(phiF[idx]));
}

// out[b][c][gp2*1024+m] = (gp2==0 ? crossT[b] : gx2T[g2])[m][c]. grid(32,16,32) block(32,8)
__global__ __launch_bounds__(256) void assemble_t(
    const u16* __restrict__ gx2T, const u16* __restrict__ crossT,
    float* __restrict__ out)
{
  int g2 = blockIdx.z, gp2 = g2 >> 3, b = g2 & 7;
  const u16* S = (gp2 == 0) ? crossT + (long)b * kPLANE : gx2T + (long)g2 * kPLANE;
  __shared__ u16 t[32][33];
  int m0 = blockIdx.x * 32, c0 = blockIdx.y * 32;
  int tx = threadIdx.x, ty = threadIdx.y;
  for (int r = ty; r < 32; r += 8) t[r][tx] = S[(long)(m0 + r) * 512 + c0 + tx];
  __syncthreads();
  for (int r = ty; r < 32; r += 8)
    out[((long)b * 512 + c0 + r) * 4096 + gp2 * 1024 + m0 + tx] = bf2f(t[tx][r]);
}

extern "C" void kernel_launch(void* const* d_in, const int* in_sizes, int n_in,
                              void* d_out, int out_size, void* d_ws, size_t ws_size,
                              hipStream_t stream)
{
  const float* feat = (const float*)d_in[0];
  const float* tg1 = (const float*)d_in[4];  const float* tb1 = (const float*)d_in[5];
  const float* tf1b = (const float*)d_in[7];
  const float* tf2b = (const float*)d_in[9];
  const float* tg2 = (const float*)d_in[10]; const float* tb2 = (const float*)d_in[11];
  const float* cg1 = (const float*)d_in[16]; const float* cb1 = (const float*)d_in[17];
  const float* cf1b = (const float*)d_in[19];
  const float* cf2b = (const float*)d_in[21];
  const float* cg2 = (const float*)d_in[22]; const float* cb2 = (const float*)d_in[23];

  // ---- ws layout (peak 112 MiB) ----
  char* wsb = (char*)d_ws;
  u16* WP = (u16*)wsb;                 // 7 proj weights (d,c) bf16: 3.5 MiB
  u16* WF = (u16*)(wsb + 4 * MB);      // 4 FFN weights bf16: 8 MiB
  float* SM = (float*)(wsb + 12 * MB); // fp32 smalls
  float* QG = SM;                      // 32*512
  float* SC = SM + 16384;              // 32*1024
  float* AL = SM + 49152;              // 32*1024
  float* KS = SM + 81920;              // 32*512
  float* Zb = SM + 98304;              // 32*1024
  float* ZR = SM + 131072;             // 24*1024
  float* YB = SM + 155648;             // 1024*512 fp32
  u16* P2 = (u16*)(wsb + 16 * MB);     // 32 planes
  u16* P3 = (u16*)(wsb + 48 * MB);     // 32 planes
  u16* P4 = (u16*)(wsb + 80 * MB);     // 32 planes (ends 112 MiB)

  // ---- d_out (64 MiB) doubles as scratch until final assemble ----
  char* ob = (char*)d_out;
  u16* KV  = (u16*)ob;                 // SA kvT: 16 MiB
  u16* GXT = (u16*)(ob + 16 * MB);     // gxT: 32 MiB (dead after y GEMM)
  u16* HID = (u16*)ob;                 // FFN hidden chunk: 64 MiB (kv+gxT dead)
  u16* KV2 = (u16*)(ob + 32 * MB);     // cross kvT: 4 MiB
  u16* PHF = (u16*)(ob + 36 * MB);     // phi_first: 8 MiB
  u16* K0S = (u16*)(ob + 44 * MB);     // k0*alpha (c,n): 8 MiB
  u16* V0S = (u16*)(ob + 52 * MB);     // v0 (c,n): 8 MiB

  u16 *WPqk = WP,           *WPv  = WP + SZW,     *WPphi = WP + 2 * SZW,
      *WPcq = WP + 3 * SZW, *WPck = WP + 4 * SZW, *WPcv  = WP + 5 * SZW,
      *WPcphi = WP + 6 * SZW;
  u16 *WF1 = WF, *WF2 = WF + 1048576, *WF3 = WF + 2097152, *WF4 = WF + 3145728;

  dim3 b256(256), bT(32, 8);
  const float rsc = 1.0f / sqrtf(512.0f);
  const long PL = kPLANE;

  // 0. weight casts, batched (no transposes needed in NT world)
  cast7<<<dim3(1024, 7), b256, 0, stream>>>(
      (const float*)d_in[1], (const float*)d_in[2], (const float*)d_in[3],
      (const float*)d_in[12], (const float*)d_in[13], (const float*)d_in[14],
      (const float*)d_in[15], WP);
  cast4<<<dim3(4096, 4), b256, 0, stream>>>(
      (const float*)d_in[6], (const float*)d_in[8],
      (const float*)d_in[18], (const float*)d_in[20], WF);

  // ---------------- SA block (all tensors (g,n,c) T-layout) ----------------
  gather_feat<<<dim3(32, 16, 8), bT, 0, stream>>>(feat, GXT);
  // qT = phi(gxT . Wqk^T)
  gemm_mfma<<<dim3(4, 8, 32), b256, 0, stream>>>(GXT, PL, 31, WPqk, 0, 0, P2, PL,
      1024, 512, 512, 1.f, 2, nullptr, nullptr, 0, nullptr, nullptr);
  colsum<<<dim3(2, 32), b256, 0, stream>>>(P2, PL, nullptr, QG, 1.f / 1024.f);
  rowdot<<<dim3(256, 32), b256, 0, stream>>>(P2, PL, QG, 31, SC, 0);
  softmax_row<<<32, b256, 0, stream>>>(SC, AL);
  // vT, then transpose v and k'=q*alpha into (c,n) layout for kv GEMM
  gemm_mfma<<<dim3(4, 8, 32), b256, 0, stream>>>(GXT, PL, 31, WPv, 0, 0, P3, PL,
      1024, 512, 512, 1.f, 0, nullptr, nullptr, 0, nullptr, nullptr);
  transpose_b<<<dim3(32, 16, 32), bT, 0, stream>>>(P3, P4, nullptr);  // v
  transpose_b<<<dim3(32, 16, 32), bT, 0, stream>>>(P2, P3, AL);       // k'
  // kvT[d][c] = sum_n v[d][n] k'[c][n] * rsc
  gemm_mfma<<<dim3(4, 4, 32), b256, 0, stream>>>(P4, PL, 31, P3, PL, 31, KV, SZW,
      512, 512, 1024, rsc, 0, nullptr, nullptr, 0, nullptr, nullptr);
  colsum<<<dim3(2, 32), b256, 0, stream>>>(P2, PL, AL, KS, 1.f);
  rowdot<<<dim3(256, 32), b256, 0, stream>>>(P2, PL, KS, 31, Zb, 1);
  // phixT
  gemm_mfma<<<dim3(4, 8, 32), b256, 0, stream>>>(GXT, PL, 31, WPphi, 0, 0, P4, PL,
      1024, 512, 512, 1.f, 0, nullptr, nullptr, 0, nullptr, nullptr);
  // h_preT = qT.kvT * z[n] * phixT + gxT
  gemm_mfma<<<dim3(4, 8, 32), b256, 0, stream>>>(P2, PL, 31, KV, SZW, 31, P3, PL,
      1024, 512, 512, 1.f, 0, nullptr, Zb, 1024, P4, GXT);
  ln_rows<<<32768, b256, 0, stream>>>(P3, tg1, tb1, P2, 0);
  // FFN 512->2048->512, 2 chunks of 16384 rows (HID = full 64 MiB d_out)
  for (int ch = 0; ch < 2; ++ch) {
    const u16* Hc = P2 + (long)ch * 16 * PL;
    gemm_mfma<<<dim3(16, 128, 1), b256, 0, stream>>>(Hc, 0, 0, WF1, 0, 0, HID, 0,
        16384, 2048, 512, 1.f, 1, tf1b, nullptr, 0, nullptr, nullptr);
    gemm_mfma<<<dim3(4, 128, 1), b256, 0, stream>>>(HID, 0, 0, WF2, 0, 0,
        P3 + (long)ch * 16 * PL, 0, 16384, 512, 2048, 1.f, 0, tf2b, nullptr, 0, nullptr, Hc);
  }
  ln_gather<<<32768, b256, 0, stream>>>(P3, tg2, tb2, P4);        // t_saT -> gx2T fused

  // ---------------- cross block ----------------
  gemm_mfma<<<dim3(4, 8, 24), b256, 0, stream>>>(P4 + 8 * PL, PL, 31, WPcq, 0, 0, P2, PL,
      1024, 512, 512, 1.f, 2, nullptr, nullptr, 0, nullptr, nullptr);        // q_restT
  gemm_mfma<<<dim3(4, 8, 24), b256, 0, stream>>>(P4 + 8 * PL, PL, 31, WPcphi, 0, 0, P3, PL,
      1024, 512, 512, 1.f, 0, nullptr, nullptr, 0, nullptr, nullptr);        // phi_restT
  gemm_mfma<<<dim3(4, 8, 8), b256, 0, stream>>>(P4, PL, 31, WPck, 0, 0, P2 + 24 * PL, PL,
      1024, 512, 512, 1.f, 2, nullptr, nullptr, 0, nullptr, nullptr);        // k0T
  gemm_mfma<<<dim3(4, 8, 8), b256, 0, stream>>>(P4, PL, 31, WPcv, 0, 0, P3 + 24 * PL, PL,
      1024, 512, 512, 1.f, 0, nullptr, nullptr, 0, nullptr, nullptr);        // v0T
  gemm_mfma<<<dim3(4, 8, 8), b256, 0, stream>>>(P4, PL, 31, WPcphi, 0, 0, PHF, PL,
      1024, 512, 512, 1.f, 0, nullptr, nullptr, 0, nullptr, nullptr);        // phi_firstT
  colsum<<<dim3(2, 8), b256, 0, stream>>>(P2 + 24 * PL, PL, nullptr, QG, 1.f / 1024.f);
  rowdot<<<dim3(256, 8), b256, 0, stream>>>(P2 + 24 * PL, PL, QG, 7, SC, 0);
  softmax_row<<<8, b256, 0, stream>>>(SC, AL);
  transpose_b<<<dim3(32, 16, 8), bT, 0, stream>>>(P2 + 24 * PL, K0S, AL);  // k0'
  transpose_b<<<dim3(32, 16, 8), bT, 0, stream>>>(P3 + 24 * PL, V0S, nullptr);
  gemm_mfma<<<dim3(4, 4, 8), b256, 0, stream>>>(V0S, PL, 31, K0S, PL, 31, KV2, SZW,
      512, 512, 1024, rsc, 0, nullptr, nullptr, 0, nullptr, nullptr);
  colsum<<<dim3(2, 8), b256, 0, stream>>>(P2 + 24 * PL, PL, AL, KS, 1.f);
  rowdot<<<dim3(256, 24), b256, 0, stream>>>(P2, PL, KS, 7, ZR, 1);
  // y_restT = q_restT.kvT2[g&7] * z[n] * phi_restT  (in-place into P3)
  gemm_mfma<<<dim3(4, 8, 24), b256, 0, stream>>>(P2, PL, 31, KV2, SZW, 7, P3, PL,
      1024, 512, 512, 1.f, 0, nullptr, ZR, 1024, P3, nullptr);
  ybar_k<<<2048, b256, 0, stream>>>(P3, YB);
  hfirst_k<<<16384, b256, 0, stream>>>(P4, PHF, YB, P2 + 24 * PL);   // h_first
  ln_rows<<<8192, b256, 0, stream>>>(P2 + 24 * PL, cg1, cb1, P3 + 24 * PL, 0);
  gemm_mfma<<<dim3(16, 64, 1), b256, 0, stream>>>(P3 + 24 * PL, 0, 0, WF3, 0, 0, HID, 0,
      8192, 2048, 512, 1.f, 1, cf1b, nullptr, 0, nullptr, nullptr);
  gemm_mfma<<<dim3(4, 64, 1), b256, 0, stream>>>(HID, 0, 0, WF4, 0, 0, P2 + 24 * PL, 0,
      8192, 512, 2048, 1.f, 0, cf2b, nullptr, 0, nullptr, P3 + 24 * PL);
  ln_rows<<<8192, b256, 0, stream>>>(P2 + 24 * PL, cg2, cb2, P3 + 24 * PL, 1); // crossT
  assemble_t<<<dim3(32, 16, 32), bT, 0, stream>>>(P4, P3 + 24 * PL, (float*)d_out);
}

// Round 5
// 956.050 us; speedup vs baseline: 1.3850x; 1.2390x over previous
//
#include <hip/hip_runtime.h>
#include <math.h>

using u16 = unsigned short;
typedef __attribute__((ext_vector_type(8))) short short8;
typedef __attribute__((ext_vector_type(4))) float f32x4;

// B=8, C=512, N=4096, GP=4 -> G=32 groups, NG=1024, F=2048
constexpr long kPLANE = 1024l * 512;     // elems per (g) plane, T-layout (n, c)
constexpr long SZW    = 512l * 512;
constexpr long MB     = 1l << 20;

__device__ __forceinline__ float bf2f(u16 u) {
  return __uint_as_float(((unsigned int)u) << 16);
}
__device__ __forceinline__ u16 f2bf(float f) {
  unsigned int x = __float_as_uint(f);
  x += 0x7fffu + ((x >> 16) & 1u);
  return (u16)(x >> 16);
}

// ---------------------------------------------------------------------------
// Unified MFMA GEMM (NT form): Out[g][m][n] = epi( scale * sum_k A[m][k]*B[n][k] )
// A (M x K) bf16 K-contig, B (N x K) bf16 K-contig. 128x128 tile, BK=32,
// 4 waves each 64x64 via 4x4 v_mfma_f32_16x16x32_bf16.
// Register staging, depth-1 prefetch, one barrier per K-step.
// __launch_bounds__(256,4): cap 128 unified regs/wave -> ~4 blocks/CU.
// + XCD-aware bijective block swizzle (A-panel sharers in one L2).
// + LDS chunk XOR-swizzle (both-sides): bank-conflict-free ds_read_b128.
// epi: *rowscale[g][m] -> *pmul[g][m][n] -> +bias[n] -> +resid[g][m][n] -> act
// act: 0 none, 1 relu, 2 relu+1 (phi). pmul may alias Out.
// ---------------------------------------------------------------------------
__global__ __launch_bounds__(256, 4) void gemm_mfma(
    const u16* __restrict__ A, long sA, int amask,
    const u16* __restrict__ B, long sB, int bmask,
    u16* __restrict__ Out, long sO,
    int M, int Nn, int K, float scale, int act,
    const float* __restrict__ bias,
    const float* __restrict__ rowscale, long sRS,
    const u16* __restrict__ pmul, const u16* __restrict__ resid)
{
  // XCD-aware bijective remap (m204): linearize grid, chunk over 8 XCDs.
  int gx = gridDim.x, gy = gridDim.y;
  int nwg = gx * gy * gridDim.z;
  int lin = blockIdx.x + gx * (blockIdx.y + gy * blockIdx.z);
  int qq = nwg >> 3, rr = nwg & 7;
  int xcd = lin & 7, idx = lin >> 3;
  int wg = (xcd < rr ? xcd * (qq + 1) : rr * (qq + 1) + (xcd - rr) * qq) + idx;
  int bx = wg % gx; int t_ = wg / gx; int by = t_ % gy; int g = t_ / gy;

  const u16* Ag = A + (long)(g & amask) * sA;
  const u16* Bg = B + (long)(g & bmask) * sB;
  u16* Og = Out + (long)g * sO;
  int m0 = by * 128, n0 = bx * 128;

  __shared__ __align__(16) u16 As[2][128 * 32];
  __shared__ __align__(16) u16 Bs[2][128 * 32];

  int tid = threadIdx.x;
  int w = tid >> 6, L = tid & 63;
  int wm = (w >> 1) * 64, wn = (w & 1) * 64;
  int l15 = L & 15, l4 = L >> 4;

  f32x4 acc[4][4] = {};

  // staging: 512 16B-chunks per 128x32 tile; thread covers chunks tid, tid+256.
  // LDS slot: row r keeps its 64B but its four 16B chunks are permuted by
  // c' = c ^ ((r>>1)&3).
  int r0 = tid >> 2, r1 = r0 + 64;
  int kk = (tid & 3) * 8;
  int cxor = (tid >> 3) & 3;
  int s0 = r0 * 32 + (((tid & 3) ^ cxor) << 3);
  int s1 = s0 + 64 * 32;
  const u16* gA0 = Ag + (long)(m0 + r0) * K + kk;
  const u16* gA1 = Ag + (long)(m0 + r1) * K + kk;
  const u16* gB0 = Bg + (long)(n0 + r0) * K + kk;
  const u16* gB1 = Bg + (long)(n0 + r1) * K + kk;

  // fragment-read column with matching swizzle.
  int rcol = (l4 << 3) ^ (((l15 >> 1) & 3) << 3);

  // preload tile 0 into LDS buffer 0
  short8 ra0 = *(const short8*)gA0;
  short8 ra1 = *(const short8*)gA1;
  short8 rb0 = *(const short8*)gB0;
  short8 rb1 = *(const short8*)gB1;
  *(short8*)&As[0][s0] = ra0; *(short8*)&As[0][s1] = ra1;
  *(short8*)&Bs[0][s0] = rb0; *(short8*)&Bs[0][s1] = rb1;
  __syncthreads();

  int nsteps = K >> 5;
  for (int ks = 0; ks < nsteps; ++ks) {
    int cur = ks & 1;
    if (ks + 1 < nsteps) {             // prefetch next K-tile into registers
      int ko = (ks + 1) << 5;
      ra0 = *(const short8*)(gA0 + ko);
      ra1 = *(const short8*)(gA1 + ko);
      rb0 = *(const short8*)(gB0 + ko);
      rb1 = *(const short8*)(gB1 + ko);
    }
    short8 af[4], bf[4];
#pragma unroll
    for (int mi = 0; mi < 4; ++mi)
      af[mi] = *(const short8*)&As[cur][(wm + mi * 16 + l15) * 32 + rcol];
#pragma unroll
    for (int ni = 0; ni < 4; ++ni)
      bf[ni] = *(const short8*)&Bs[cur][(wn + ni * 16 + l15) * 32 + rcol];
#pragma unroll
    for (int mi = 0; mi < 4; ++mi)
#pragma unroll
      for (int ni = 0; ni < 4; ++ni)
        acc[mi][ni] = __builtin_amdgcn_mfma_f32_16x16x32_bf16(bf[ni], af[mi], acc[mi][ni], 0, 0, 0);
    if (ks + 1 < nsteps) {             // write prefetched tile to other buffer
      int nxt = cur ^ 1;
      *(short8*)&As[nxt][s0] = ra0; *(short8*)&As[nxt][s1] = ra1;
      *(short8*)&Bs[nxt][s0] = rb0; *(short8*)&Bs[nxt][s1] = rb1;
    }
    __syncthreads();
  }

  // epilogue (operand-swapped D): lane holds n = nb..nb+3 at fixed m
#pragma unroll
  for (int mi = 0; mi < 4; ++mi) {
    int m = m0 + wm + mi * 16 + l15;
    float rs = rowscale ? rowscale[(long)g * sRS + m] : 1.f;
    float srs = scale * rs;
#pragma unroll
    for (int ni = 0; ni < 4; ++ni) {
      int nb = n0 + wn + ni * 16 + l4 * 4;
      long off = (long)m * Nn + nb;
      float v[4];
#pragma unroll
      for (int r = 0; r < 4; ++r) v[r] = acc[mi][ni][r] * srs;
      if (pmul) {
        ushort4 pm = *(const ushort4*)&pmul[(long)g * sO + off];
        v[0] *= bf2f(pm.x); v[1] *= bf2f(pm.y); v[2] *= bf2f(pm.z); v[3] *= bf2f(pm.w);
      }
      if (bias) {
        float4 bi = *(const float4*)&bias[nb];
        v[0] += bi.x; v[1] += bi.y; v[2] += bi.z; v[3] += bi.w;
      }
      if (resid) {
        ushort4 rd = *(const ushort4*)&resid[(long)g * sO + off];
        v[0] += bf2f(rd.x); v[1] += bf2f(rd.y); v[2] += bf2f(rd.z); v[3] += bf2f(rd.w);
      }
      if (act == 1) {
#pragma unroll
        for (int r = 0; r < 4; ++r) v[r] = fmaxf(v[r], 0.f);
      } else if (act == 2) {
#pragma unroll
        for (int r = 0; r < 4; ++r) v[r] = fmaxf(v[r], 0.f) + 1.f;
      }
      ushort4 o; o.x = f2bf(v[0]); o.y = f2bf(v[1]); o.z = f2bf(v[2]); o.w = f2bf(v[3]);
      *(ushort4*)&Og[off] = o;
    }
  }
}

// fp32 -> bf16 batched casts: 7 proj weights (262144 each) in one launch
__global__ __launch_bounds__(256) void cast7(
    const float* a0, const float* a1, const float* a2, const float* a3,
    const float* a4, const float* a5, const float* a6, u16* __restrict__ dst)
{
  int w = blockIdx.y;
  const float* s = w == 0 ? a0 : w == 1 ? a1 : w == 2 ? a2 : w == 3 ? a3
                 : w == 4 ? a4 : w == 5 ? a5 : a6;
  long i = (long)blockIdx.x * 256 + threadIdx.x;
  dst[(long)w * SZW + i] = f2bf(s[i]);
}

// 4 FFN weights (1048576 each) in one launch
__global__ __launch_bounds__(256) void cast4(
    const float* a0, const float* a1, const float* a2, const float* a3,
    u16* __restrict__ dst)
{
  int w = blockIdx.y;
  const float* s = w == 0 ? a0 : w == 1 ? a1 : w == 2 ? a2 : a3;
  long i = (long)blockIdx.x * 256 + threadIdx.x;
  dst[(long)w * 1048576 + i] = f2bf(s[i]);
}

// gxT[gp*8+b][n][c] = feat[b][c][4n+gp]  (fp32 -> bf16). grid(32,16,8) block(32,8)
__global__ __launch_bounds__(256) void gather_feat(
    const float* __restrict__ feat, u16* __restrict__ gxT)
{
  __shared__ float t[32][132];
  int b = blockIdx.z, c0 = blockIdx.y * 32, nf0 = blockIdx.x * 128;
  int tx = threadIdx.x, ty = threadIdx.y;
  for (int r = ty; r < 32; r += 8)
    *(float4*)&t[r][tx * 4] = *(const float4*)&feat[((long)b * 512 + c0 + r) * 4096 + nf0 + tx * 4];
  __syncthreads();
  int n0o = nf0 >> 2;
  for (int gp = 0; gp < 4; ++gp) {
    long gbase = (long)(gp * 8 + b) * kPLANE;
    for (int jr = ty; jr < 32; jr += 8)
      gxT[gbase + (long)(n0o + jr) * 512 + c0 + tx] = f2bf(t[tx][jr * 4 + gp]);
  }
}

// out[g][c][n] = in[g][n][c] * (alpha ? alpha[g][n] : 1).
// 64x64 tile, ushort2 I/O (4B/lane). grid(16, 8, G) block(32,8)
__global__ __launch_bounds__(256) void transpose_b(
    const u16* __restrict__ in, u16* __restrict__ out, const float* __restrict__ alpha)
{
  int g = blockIdx.z;
  const u16* I = in + (long)g * kPLANE;
  u16* O = out + (long)g * kPLANE;
  __shared__ u16 t[64][66];
  int n0 = blockIdx.x * 64, c0 = blockIdx.y * 64;
  int tx = threadIdx.x, ty = threadIdx.y;
  for (int r = ty; r < 64; r += 8)
    *(ushort2*)&t[r][tx * 2] = *(const ushort2*)&I[(long)(n0 + r) * 512 + c0 + tx * 2];
  __syncthreads();
  float al0 = 1.f, al1 = 1.f;
  if (alpha) {
    al0 = alpha[(long)g * 1024 + n0 + tx * 2];
    al1 = alpha[(long)g * 1024 + n0 + tx * 2 + 1];
  }
  for (int r = ty; r < 64; r += 8) {
    ushort2 wv;
    wv.x = f2bf(bf2f(t[tx * 2][r]) * al0);
    wv.y = f2bf(bf2f(t[tx * 2 + 1][r]) * al1);
    *(ushort2*)&O[(long)(c0 + r) * 1024 + n0 + tx * 2] = wv;
  }
}

// colsum stage 1: part[g*8+ch][c] = sum_{n in chunk ch} X[g][n][c]*alpha?
// grid(2, 8, G) block 256
__global__ __launch_bounds__(256) void colsum1(
    const u16* __restrict__ X, long sX, const float* __restrict__ alpha,
    float* __restrict__ part)
{
  int g = blockIdx.z, ch = blockIdx.y;
  int c = blockIdx.x * 256 + threadIdx.x;
  const u16* Xg = X + (long)g * sX;
  int nb = ch * 128;
  float s = 0.f;
  for (int i = 0; i < 128; ++i) {
    int n = nb + i;
    s += bf2f(Xg[(long)n * 512 + c]) * (alpha ? alpha[(long)g * 1024 + n] : 1.f);
  }
  part[(long)(g * 8 + ch) * 512 + c] = s;
}

// colsum stage 2: out[g][c] = scale * sum_ch part[g*8+ch][c]. grid(2, G)
__global__ __launch_bounds__(256) void colsum2(
    const float* __restrict__ part, float* __restrict__ out, float scale)
{
  int g = blockIdx.y;
  int c = blockIdx.x * 256 + threadIdx.x;
  float s = 0.f;
#pragma unroll
  for (int ch = 0; ch < 8; ++ch) s += part[(long)(g * 8 + ch) * 512 + c];
  out[(long)g * 512 + c] = s * scale;
}

// out[g][n] = f( sum_c X[g][n][c] * w[(g&wmask)][c] ). mode1: 1/(x+1e-6). grid(256,G)
__global__ __launch_bounds__(256) void rowdot(
    const u16* __restrict__ X, long sX, const float* __restrict__ w, int wmask,
    float* __restrict__ out, int mode)
{
  int g = blockIdx.y;
  int n = blockIdx.x * 4 + (threadIdx.x >> 6);
  int L = threadIdx.x & 63;
  const u16* row = X + (long)g * sX + (long)n * 512;
  short8 xv = *(const short8*)&row[L * 8];
  const float* wg = w + (long)(g & wmask) * 512;
  float4 w0 = *(const float4*)&wg[L * 8];
  float4 w1 = *(const float4*)&wg[L * 8 + 4];
  float s = bf2f((u16)xv[0]) * w0.x + bf2f((u16)xv[1]) * w0.y +
            bf2f((u16)xv[2]) * w0.z + bf2f((u16)xv[3]) * w0.w +
            bf2f((u16)xv[4]) * w1.x + bf2f((u16)xv[5]) * w1.y +
            bf2f((u16)xv[6]) * w1.z + bf2f((u16)xv[7]) * w1.w;
#pragma unroll
  for (int off = 32; off >= 1; off >>= 1) s += __shfl_down(s, off);
  if (L == 0) out[(long)g * 1024 + n] = mode ? 1.f / (s + 1e-6f) : s;
}

// alpha[g][n] = softmax_n(sc[g])[n] * 1024. grid(G)
__global__ __launch_bounds__(256) void softmax_row(
    const float* __restrict__ sc, float* __restrict__ out)
{
  int g = blockIdx.x, tid = threadIdx.x;
  const float* s = sc + (long)g * 1024;
  float* o = out + (long)g * 1024;
  __shared__ float red[256];
  float lm = -3.4e38f;
  for (int n = tid; n < 1024; n += 256) lm = fmaxf(lm, s[n]);
  red[tid] = lm; __syncthreads();
  for (int st = 128; st; st >>= 1) { if (tid < st) red[tid] = fmaxf(red[tid], red[tid + st]); __syncthreads(); }
  float mx = red[0]; __syncthreads();
  float ls = 0.f;
  for (int n = tid; n < 1024; n += 256) ls += __expf(s[n] - mx);
  red[tid] = ls; __syncthreads();
  for (int st = 128; st; st >>= 1) { if (tid < st) red[tid] += red[tid + st]; __syncthreads(); }
  float inv = 1024.f / red[0];
  for (int n = tid; n < 1024; n += 256) o[n] = __expf(s[n] - mx) * inv;
}

// Wave-per-row LayerNorm over 512-wide rows. 4 rows/block, 16B/lane I/O,
// shuffle butterfly reduce, zero barriers. grid = rows/4.
__global__ __launch_bounds__(256) void ln_rows(
    const u16* __restrict__ X, const float* __restrict__ gamma,
    const float* __restrict__ beta, u16* __restrict__ Out, int relu)
{
  long m = (long)blockIdx.x * 4 + (threadIdx.x >> 6);
  int L = threadIdx.x & 63;
  const u16* x = X + m * 512;
  u16* o = Out + m * 512;
  short8 xv = *(const short8*)&x[L * 8];
  float v[8];
#pragma unroll
  for (int j = 0; j < 8; ++j) v[j] = bf2f((u16)xv[j]);
  float s = v[0] + v[1] + v[2] + v[3] + v[4] + v[5] + v[6] + v[7];
#pragma unroll
  for (int off = 32; off >= 1; off >>= 1) s += __shfl_xor(s, off);
  float mu = s * (1.f / 512.f);
  float ss = 0.f;
#pragma unroll
  for (int j = 0; j < 8; ++j) { v[j] -= mu; ss += v[j] * v[j]; }
#pragma unroll
  for (int off = 32; off >= 1; off >>= 1) ss += __shfl_xor(ss, off);
  float rs = rsqrtf(ss * (1.f / 512.f) + 1e-6f);
  float4 g0 = *(const float4*)&gamma[L * 8];
  float4 g1 = *(const float4*)&gamma[L * 8 + 4];
  float4 b0 = *(const float4*)&beta[L * 8];
  float4 b1 = *(const float4*)&beta[L * 8 + 4];
  float ov[8];
  ov[0] = v[0] * rs * g0.x + b0.x; ov[1] = v[1] * rs * g0.y + b0.y;
  ov[2] = v[2] * rs * g0.z + b0.z; ov[3] = v[3] * rs * g0.w + b0.w;
  ov[4] = v[4] * rs * g1.x + b1.x; ov[5] = v[5] * rs * g1.y + b1.y;
  ov[6] = v[6] * rs * g1.z + b1.z; ov[7] = v[7] * rs * g1.w + b1.w;
  if (relu) {
#pragma unroll
    for (int j = 0; j < 8; ++j) ov[j] = fmaxf(ov[j], 0.f);
  }
  short8 r;
#pragma unroll
  for (int j = 0; j < 8; ++j) r[j] = (short)f2bf(ov[j]);
  *(short8*)&o[L * 8] = r;
}

// Fused: Out[g2][m] = relu(LN(X[srcrow(g2,m)])) with the gather_x2 row map.
// Wave-per-row. grid = 32768/4 = 8192.
__global__ __launch_bounds__(256) void ln_gather(
    const u16* __restrict__ X, const float* __restrict__ gamma,
    const float* __restrict__ beta, u16* __restrict__ Out)
{
  long bid = (long)blockIdx.x * 4 + (threadIdx.x >> 6);
  int L = threadIdx.x & 63;
  int g2 = (int)(bid >> 10), m = (int)(bid & 1023);
  long src = ((long)((m & 3) * 8 + (g2 & 7)) * 1024 + (g2 >> 3) * 256 + (m >> 2)) * 512;
  const u16* x = X + src;
  u16* o = Out + bid * 512;
  short8 xv = *(const short8*)&x[L * 8];
  float v[8];
#pragma unroll
  for (int j = 0; j < 8; ++j) v[j] = bf2f((u16)xv[j]);
  float s = v[0] + v[1] + v[2] + v[3] + v[4] + v[5] + v[6] + v[7];
#pragma unroll
  for (int off = 32; off >= 1; off >>= 1) s += __shfl_xor(s, off);
  float mu = s * (1.f / 512.f);
  float ss = 0.f;
#pragma unroll
  for (int j = 0; j < 8; ++j) { v[j] -= mu; ss += v[j] * v[j]; }
#pragma unroll
  for (int off = 32; off >= 1; off >>= 1) ss += __shfl_xor(ss, off);
  float rs = rsqrtf(ss * (1.f / 512.f) + 1e-6f);
  float4 g0 = *(const float4*)&gamma[L * 8];
  float4 g1 = *(const float4*)&gamma[L * 8 + 4];
  float4 b0 = *(const float4*)&beta[L * 8];
  float4 b1 = *(const float4*)&beta[L * 8 + 4];
  float ov[8];
  ov[0] = v[0] * rs * g0.x + b0.x; ov[1] = v[1] * rs * g0.y + b0.y;
  ov[2] = v[2] * rs * g0.z + b0.z; ov[3] = v[3] * rs * g0.w + b0.w;
  ov[4] = v[4] * rs * g1.x + b1.x; ov[5] = v[5] * rs * g1.y + b1.y;
  ov[6] = v[6] * rs * g1.z + b1.z; ov[7] = v[7] * rs * g1.w + b1.w;
  short8 r;
#pragma unroll
  for (int j = 0; j < 8; ++j) r[j] = (short)f2bf(fmaxf(ov[j], 0.f));
  *(short8*)&o[L * 8] = r;
}

// ybar = mean over 24 planes, 2 elems/thread (bf16 in, fp32 out). grid 1024
__global__ __launch_bounds__(256) void ybar_k(
    const u16* __restrict__ Y, float* __restrict__ yb)
{
  long idx = ((long)blockIdx.x * 256 + threadIdx.x) * 2;
  float s0 = 0.f, s1 = 0.f;
#pragma unroll
  for (int g = 0; g < 24; ++g) {
    ushort2 u = *(const ushort2*)&Y[(long)g * kPLANE + idx];
    s0 += bf2f(u.x); s1 += bf2f(u.y);
  }
  float2 o; o.x = s0 * (1.f / 24.f); o.y = s1 * (1.f / 24.f);
  *(float2*)&yb[idx] = o;
}

// h_first[b][n][c] = gx2T[b][n][c] + ybar[n][c]*phiF[b][n][c]. 2/thread. grid 8192
__global__ __launch_bounds__(256) void hfirst_k(
    const u16* __restrict__ gx2, const u16* __restrict__ phiF,
    const float* __restrict__ yb, u16* __restrict__ h)
{
  long idx = ((long)blockIdx.x * 256 + threadIdx.x) * 2;
  long p = idx & (kPLANE - 1);
  ushort2 a = *(const ushort2*)&gx2[idx];
  ushort2 f = *(const ushort2*)&phiF[idx];
  float2 y = *(const float2*)&yb[p];
  ushort2 o;
  o.x = f2bf(bf2f(a.x) + y.x * bf2f(f.x));
  o.y = f2bf(bf2f(a.y) + y.y * bf2f(f.y));
  *(ushort2*)&h[idx] = o;
}

// out[b][c][gp2*1024+m] = (gp2==0 ? crossT[b] : gx2T[g2])[m][c]. grid(32,16,32) block(32,8)
__global__ __launch_bounds__(256) void assemble_t(
    const u16* __restrict__ gx2T, const u16* __restrict__ crossT,
    float* __restrict__ out)
{
  int g2 = blockIdx.z, gp2 = g2 >> 3, b = g2 & 7;
  const u16* S = (gp2 == 0) ? crossT + (long)b * kPLANE : gx2T + (long)g2 * kPLANE;
  __shared__ u16 t[32][33];
  int m0 = blockIdx.x * 32, c0 = blockIdx.y * 32;
  int tx = threadIdx.x, ty = threadIdx.y;
  for (int r = ty; r < 32; r += 8) t[r][tx] = S[(long)(m0 + r) * 512 + c0 + tx];
  __syncthreads();
  for (int r = ty; r < 32; r += 8)
    out[((long)b * 512 + c0 + r) * 4096 + gp2 * 1024 + m0 + tx] = bf2f(t[tx][r]);
}

extern "C" void kernel_launch(void* const* d_in, const int* in_sizes, int n_in,
                              void* d_out, int out_size, void* d_ws, size_t ws_size,
                              hipStream_t stream)
{
  const float* feat = (const float*)d_in[0];
  const float* tg1 = (const float*)d_in[4];  const float* tb1 = (const float*)d_in[5];
  const float* tf1b = (const float*)d_in[7];
  const float* tf2b = (const float*)d_in[9];
  const float* tg2 = (const float*)d_in[10]; const float* tb2 = (const float*)d_in[11];
  const float* cg1 = (const float*)d_in[16]; const float* cb1 = (const float*)d_in[17];
  const float* cf1b = (const float*)d_in[19];
  const float* cf2b = (const float*)d_in[21];
  const float* cg2 = (const float*)d_in[22]; const float* cb2 = (const float*)d_in[23];

  // ---- ws layout (peak 112 MiB) ----
  char* wsb = (char*)d_ws;
  u16* WP = (u16*)wsb;                 // 7 proj weights (d,c) bf16: 3.5 MiB
  u16* WF = (u16*)(wsb + 4 * MB);      // 4 FFN weights bf16: 8 MiB
  float* SM = (float*)(wsb + 12 * MB); // fp32 smalls
  float* QG = SM;                      // 32*512
  float* SC = SM + 16384;              // 32*1024
  float* AL = SM + 49152;              // 32*1024
  float* KS = SM + 81920;              // 32*512
  float* Zb = SM + 98304;              // 32*1024
  float* ZR = SM + 131072;             // 24*1024
  float* YB = SM + 155648;             // 1024*512 fp32 (ends 679936)
  float* PART = SM + 688128;           // colsum partials 32*8*512 (ends 819200)
  u16* P2 = (u16*)(wsb + 16 * MB);     // 32 planes
  u16* P3 = (u16*)(wsb + 48 * MB);     // 32 planes
  u16* P4 = (u16*)(wsb + 80 * MB);     // 32 planes (ends 112 MiB)

  // ---- d_out (64 MiB) doubles as scratch until final assemble ----
  char* ob = (char*)d_out;
  u16* KV  = (u16*)ob;                 // SA kvT: 16 MiB
  u16* GXT = (u16*)(ob + 16 * MB);     // gxT: 32 MiB (dead after y GEMM)
  u16* HID = (u16*)ob;                 // FFN hidden chunk: 64 MiB (kv+gxT dead)
  u16* KV2 = (u16*)(ob + 32 * MB);     // cross kvT: 4 MiB
  u16* PHF = (u16*)(ob + 36 * MB);     // phi_first: 8 MiB
  u16* K0S = (u16*)(ob + 44 * MB);     // k0*alpha (c,n): 8 MiB
  u16* V0S = (u16*)(ob + 52 * MB);     // v0 (c,n): 8 MiB

  u16 *WPqk = WP,           *WPv  = WP + SZW,     *WPphi = WP + 2 * SZW,
      *WPcq = WP + 3 * SZW, *WPck = WP + 4 * SZW, *WPcv  = WP + 5 * SZW,
      *WPcphi = WP + 6 * SZW;
  u16 *WF1 = WF, *WF2 = WF + 1048576, *WF3 = WF + 2097152, *WF4 = WF + 3145728;

  dim3 b256(256), bT(32, 8);
  const float rsc = 1.0f / sqrtf(512.0f);
  const long PL = kPLANE;

  // 0. weight casts, batched
  cast7<<<dim3(1024, 7), b256, 0, stream>>>(
      (const float*)d_in[1], (const float*)d_in[2], (const float*)d_in[3],
      (const float*)d_in[12], (const float*)d_in[13], (const float*)d_in[14],
      (const float*)d_in[15], WP);
  cast4<<<dim3(4096, 4), b256, 0, stream>>>(
      (const float*)d_in[6], (const float*)d_in[8],
      (const float*)d_in[18], (const float*)d_in[20], WF);

  // ---------------- SA block (all tensors (g,n,c) T-layout) ----------------
  gather_feat<<<dim3(32, 16, 8), bT, 0, stream>>>(feat, GXT);
  // qT = phi(gxT . Wqk^T)
  gemm_mfma<<<dim3(4, 8, 32), b256, 0, stream>>>(GXT, PL, 31, WPqk, 0, 0, P2, PL,
      1024, 512, 512, 1.f, 2, nullptr, nullptr, 0, nullptr, nullptr);
  colsum1<<<dim3(2, 8, 32), b256, 0, stream>>>(P2, PL, nullptr, PART);
  colsum2<<<dim3(2, 32), b256, 0, stream>>>(PART, QG, 1.f / 1024.f);
  rowdot<<<dim3(256, 32), b256, 0, stream>>>(P2, PL, QG, 31, SC, 0);
  softmax_row<<<32, b256, 0, stream>>>(SC, AL);
  // vT, then transpose v and k'=q*alpha into (c,n) layout for kv GEMM
  gemm_mfma<<<dim3(4, 8, 32), b256, 0, stream>>>(GXT, PL, 31, WPv, 0, 0, P3, PL,
      1024, 512, 512, 1.f, 0, nullptr, nullptr, 0, nullptr, nullptr);
  transpose_b<<<dim3(16, 8, 32), bT, 0, stream>>>(P3, P4, nullptr);  // v
  transpose_b<<<dim3(16, 8, 32), bT, 0, stream>>>(P2, P3, AL);       // k'
  // kvT[d][c] = sum_n v[d][n] k'[c][n] * rsc
  gemm_mfma<<<dim3(4, 4, 32), b256, 0, stream>>>(P4, PL, 31, P3, PL, 31, KV, SZW,
      512, 512, 1024, rsc, 0, nullptr, nullptr, 0, nullptr, nullptr);
  colsum1<<<dim3(2, 8, 32), b256, 0, stream>>>(P2, PL, AL, PART);
  colsum2<<<dim3(2, 32), b256, 0, stream>>>(PART, KS, 1.f);
  rowdot<<<dim3(256, 32), b256, 0, stream>>>(P2, PL, KS, 31, Zb, 1);
  // phixT
  gemm_mfma<<<dim3(4, 8, 32), b256, 0, stream>>>(GXT, PL, 31, WPphi, 0, 0, P4, PL,
      1024, 512, 512, 1.f, 0, nullptr, nullptr, 0, nullptr, nullptr);
  // h_preT = qT.kvT * z[n] * phixT + gxT
  gemm_mfma<<<dim3(4, 8, 32), b256, 0, stream>>>(P2, PL, 31, KV, SZW, 31, P3, PL,
      1024, 512, 512, 1.f, 0, nullptr, Zb, 1024, P4, GXT);
  ln_rows<<<8192, b256, 0, stream>>>(P3, tg1, tb1, P2, 0);
  // FFN 512->2048->512, 2 chunks of 16384 rows (HID = full 64 MiB d_out)
  for (int ch = 0; ch < 2; ++ch) {
    const u16* Hc = P2 + (long)ch * 16 * PL;
    gemm_mfma<<<dim3(16, 128, 1), b256, 0, stream>>>(Hc, 0, 0, WF1, 0, 0, HID, 0,
        16384, 2048, 512, 1.f, 1, tf1b, nullptr, 0, nullptr, nullptr);
    gemm_mfma<<<dim3(4, 128, 1), b256, 0, stream>>>(HID, 0, 0, WF2, 0, 0,
        P3 + (long)ch * 16 * PL, 0, 16384, 512, 2048, 1.f, 0, tf2b, nullptr, 0, nullptr, Hc);
  }
  ln_gather<<<8192, b256, 0, stream>>>(P3, tg2, tb2, P4);         // t_saT -> gx2T fused

  // ---------------- cross block ----------------
  gemm_mfma<<<dim3(4, 8, 24), b256, 0, stream>>>(P4 + 8 * PL, PL, 31, WPcq, 0, 0, P2, PL,
      1024, 512, 512, 1.f, 2, nullptr, nullptr, 0, nullptr, nullptr);        // q_restT
  gemm_mfma<<<dim3(4, 8, 24), b256, 0, stream>>>(P4 + 8 * PL, PL, 31, WPcphi, 0, 0, P3, PL,
      1024, 512, 512, 1.f, 0, nullptr, nullptr, 0, nullptr, nullptr);        // phi_restT
  gemm_mfma<<<dim3(4, 8, 8), b256, 0, stream>>>(P4, PL, 31, WPck, 0, 0, P2 + 24 * PL, PL,
      1024, 512, 512, 1.f, 2, nullptr, nullptr, 0, nullptr, nullptr);        // k0T
  gemm_mfma<<<dim3(4, 8, 8), b256, 0, stream>>>(P4, PL, 31, WPcv, 0, 0, P3 + 24 * PL, PL,
      1024, 512, 512, 1.f, 0, nullptr, nullptr, 0, nullptr, nullptr);        // v0T
  gemm_mfma<<<dim3(4, 8, 8), b256, 0, stream>>>(P4, PL, 31, WPcphi, 0, 0, PHF, PL,
      1024, 512, 512, 1.f, 0, nullptr, nullptr, 0, nullptr, nullptr);        // phi_firstT
  colsum1<<<dim3(2, 8, 8), b256, 0, stream>>>(P2 + 24 * PL, PL, nullptr, PART);
  colsum2<<<dim3(2, 8), b256, 0, stream>>>(PART, QG, 1.f / 1024.f);
  rowdot<<<dim3(256, 8), b256, 0, stream>>>(P2 + 24 * PL, PL, QG, 7, SC, 0);
  softmax_row<<<8, b256, 0, stream>>>(SC, AL);
  transpose_b<<<dim3(16, 8, 8), bT, 0, stream>>>(P2 + 24 * PL, K0S, AL);  // k0'
  transpose_b<<<dim3(16, 8, 8), bT, 0, stream>>>(P3 + 24 * PL, V0S, nullptr);
  gemm_mfma<<<dim3(4, 4, 8), b256, 0, stream>>>(V0S, PL, 31, K0S, PL, 31, KV2, SZW,
      512, 512, 1024, rsc, 0, nullptr, nullptr, 0, nullptr, nullptr);
  colsum1<<<dim3(2, 8, 8), b256, 0, stream>>>(P2 + 24 * PL, PL, AL, PART);
  colsum2<<<dim3(2, 8), b256, 0, stream>>>(PART, KS, 1.f);
  rowdot<<<dim3(256, 24), b256, 0, stream>>>(P2, PL, KS, 7, ZR, 1);
  // y_restT = q_restT.kvT2[g&7] * z[n] * phi_restT  (in-place into P3)
  gemm_mfma<<<dim3(4, 8, 24), b256, 0, stream>>>(P2, PL, 31, KV2, SZW, 7, P3, PL,
      1024, 512, 512, 1.f, 0, nullptr, ZR, 1024, P3, nullptr);
  ybar_k<<<1024, b256, 0, stream>>>(P3, YB);
  hfirst_k<<<8192, b256, 0, stream>>>(P4, PHF, YB, P2 + 24 * PL);   // h_first
  ln_rows<<<2048, b256, 0, stream>>>(P2 + 24 * PL, cg1, cb1, P3 + 24 * PL, 0);
  gemm_mfma<<<dim3(16, 64, 1), b256, 0, stream>>>(P3 + 24 * PL, 0, 0, WF3, 0, 0, HID, 0,
      8192, 2048, 512, 1.f, 1, cf1b, nullptr, 0, nullptr, nullptr);
  gemm_mfma<<<dim3(4, 64, 1), b256, 0, stream>>>(HID, 0, 0, WF4, 0, 0, P2 + 24 * PL, 0,
      8192, 512, 2048, 1.f, 0, cf2b, nullptr, 0, nullptr, P3 + 24 * PL);
  ln_rows<<<2048, b256, 0, stream>>>(P2 + 24 * PL, cg2, cb2, P3 + 24 * PL, 1); // crossT
  assemble_t<<<dim3(32, 16, 32), bT, 0, stream>>>(P4, P3 + 24 * PL, (float*)d_out);
}

// Round 6
// 929.714 us; speedup vs baseline: 1.4242x; 1.0283x over previous
//
#include <hip/hip_runtime.h>
#include <math.h>

using u16 = unsigned short;
typedef __attribute__((ext_vector_type(8))) short short8;
typedef __attribute__((ext_vector_type(4))) float f32x4;

// B=8, C=512, N=4096, GP=4 -> G=32 groups, NG=1024, F=2048
constexpr long kPLANE = 1024l * 512;     // elems per (g) plane, T-layout (n, c)
constexpr long SZW    = 512l * 512;
constexpr long MB     = 1l << 20;

__device__ __forceinline__ float bf2f(u16 u) {
  return __uint_as_float(((unsigned int)u) << 16);
}
__device__ __forceinline__ u16 f2bf(float f) {
  unsigned int x = __float_as_uint(f);
  x += 0x7fffu + ((x >> 16) & 1u);
  return (u16)(x >> 16);
}

// LDS-only barrier: waits ds ops (lgkmcnt) but does NOT drain vmcnt, so the
// register prefetch global loads stay in flight across the barrier (T4).
// __syncthreads() would emit s_waitcnt vmcnt(0) lgkmcnt(0) -> ~400-500 cyc
// stall per K-step waiting loads not needed until next step's ds_write.
__device__ __forceinline__ void lds_barrier() {
  asm volatile("s_waitcnt lgkmcnt(0)" ::: "memory");
  __builtin_amdgcn_s_barrier();
}

// ---------------------------------------------------------------------------
// Unified MFMA GEMM (NT form): Out[g][m][n] = epi( scale * sum_k A[m][k]*B[n][k] )
// A (M x K) bf16 K-contig, B (N x K) bf16 K-contig. 128x128 tile, BK=32,
// 4 waves each 64x64 via 4x4 v_mfma_f32_16x16x32_bf16.
// Register staging, depth-1 prefetch, one LDS-only barrier per K-step.
// __launch_bounds__(256,4): cap 128 unified regs/wave -> ~4 blocks/CU.
// + XCD-aware bijective block swizzle (A-panel sharers in one L2).
// + LDS chunk XOR-swizzle (both-sides): bank-conflict-free ds_read_b128.
// epi: *rowscale[g][m] -> *pmul[g][m][n] -> +bias[n] -> +resid[g][m][n] -> act
// act: 0 none, 1 relu, 2 relu+1 (phi). pmul may alias Out.
// ---------------------------------------------------------------------------
__global__ __launch_bounds__(256, 4) void gemm_mfma(
    const u16* __restrict__ A, long sA, int amask,
    const u16* __restrict__ B, long sB, int bmask,
    u16* __restrict__ Out, long sO,
    int M, int Nn, int K, float scale, int act,
    const float* __restrict__ bias,
    const float* __restrict__ rowscale, long sRS,
    const u16* __restrict__ pmul, const u16* __restrict__ resid)
{
  // XCD-aware bijective remap (m204): linearize grid, chunk over 8 XCDs.
  int gx = gridDim.x, gy = gridDim.y;
  int nwg = gx * gy * gridDim.z;
  int lin = blockIdx.x + gx * (blockIdx.y + gy * blockIdx.z);
  int qq = nwg >> 3, rr = nwg & 7;
  int xcd = lin & 7, idx = lin >> 3;
  int wg = (xcd < rr ? xcd * (qq + 1) : rr * (qq + 1) + (xcd - rr) * qq) + idx;
  int bx = wg % gx; int t_ = wg / gx; int by = t_ % gy; int g = t_ / gy;

  const u16* Ag = A + (long)(g & amask) * sA;
  const u16* Bg = B + (long)(g & bmask) * sB;
  u16* Og = Out + (long)g * sO;
  int m0 = by * 128, n0 = bx * 128;

  __shared__ __align__(16) u16 As[2][128 * 32];
  __shared__ __align__(16) u16 Bs[2][128 * 32];

  int tid = threadIdx.x;
  int w = tid >> 6, L = tid & 63;
  int wm = (w >> 1) * 64, wn = (w & 1) * 64;
  int l15 = L & 15, l4 = L >> 4;

  f32x4 acc[4][4] = {};

  // staging: 512 16B-chunks per 128x32 tile; thread covers chunks tid, tid+256.
  // LDS slot: row r keeps its 64B but its four 16B chunks are permuted by
  // c' = c ^ ((r>>1)&3).
  int r0 = tid >> 2, r1 = r0 + 64;
  int kk = (tid & 3) * 8;
  int cxor = (tid >> 3) & 3;
  int s0 = r0 * 32 + (((tid & 3) ^ cxor) << 3);
  int s1 = s0 + 64 * 32;
  const u16* gA0 = Ag + (long)(m0 + r0) * K + kk;
  const u16* gA1 = Ag + (long)(m0 + r1) * K + kk;
  const u16* gB0 = Bg + (long)(n0 + r0) * K + kk;
  const u16* gB1 = Bg + (long)(n0 + r1) * K + kk;

  // fragment-read column with matching swizzle.
  int rcol = (l4 << 3) ^ (((l15 >> 1) & 3) << 3);

  // preload tile 0 into LDS buffer 0
  short8 ra0 = *(const short8*)gA0;
  short8 ra1 = *(const short8*)gA1;
  short8 rb0 = *(const short8*)gB0;
  short8 rb1 = *(const short8*)gB1;
  *(short8*)&As[0][s0] = ra0; *(short8*)&As[0][s1] = ra1;
  *(short8*)&Bs[0][s0] = rb0; *(short8*)&Bs[0][s1] = rb1;
  lds_barrier();

  int nsteps = K >> 5;
  for (int ks = 0; ks < nsteps; ++ks) {
    int cur = ks & 1;
    if (ks + 1 < nsteps) {             // prefetch next K-tile into registers
      int ko = (ks + 1) << 5;
      ra0 = *(const short8*)(gA0 + ko);
      ra1 = *(const short8*)(gA1 + ko);
      rb0 = *(const short8*)(gB0 + ko);
      rb1 = *(const short8*)(gB1 + ko);
    }
    short8 af[4], bf[4];
#pragma unroll
    for (int mi = 0; mi < 4; ++mi)
      af[mi] = *(const short8*)&As[cur][(wm + mi * 16 + l15) * 32 + rcol];
#pragma unroll
    for (int ni = 0; ni < 4; ++ni)
      bf[ni] = *(const short8*)&Bs[cur][(wn + ni * 16 + l15) * 32 + rcol];
#pragma unroll
    for (int mi = 0; mi < 4; ++mi)
#pragma unroll
      for (int ni = 0; ni < 4; ++ni)
        acc[mi][ni] = __builtin_amdgcn_mfma_f32_16x16x32_bf16(bf[ni], af[mi], acc[mi][ni], 0, 0, 0);
    if (ks + 1 < nsteps) {             // write prefetched tile to other buffer
      int nxt = cur ^ 1;
      *(short8*)&As[nxt][s0] = ra0; *(short8*)&As[nxt][s1] = ra1;
      *(short8*)&Bs[nxt][s0] = rb0; *(short8*)&Bs[nxt][s1] = rb1;
    }
    lds_barrier();
  }

  // epilogue (operand-swapped D): lane holds n = nb..nb+3 at fixed m
#pragma unroll
  for (int mi = 0; mi < 4; ++mi) {
    int m = m0 + wm + mi * 16 + l15;
    float rs = rowscale ? rowscale[(long)g * sRS + m] : 1.f;
    float srs = scale * rs;
#pragma unroll
    for (int ni = 0; ni < 4; ++ni) {
      int nb = n0 + wn + ni * 16 + l4 * 4;
      long off = (long)m * Nn + nb;
      float v[4];
#pragma unroll
      for (int r = 0; r < 4; ++r) v[r] = acc[mi][ni][r] * srs;
      if (pmul) {
        ushort4 pm = *(const ushort4*)&pmul[(long)g * sO + off];
        v[0] *= bf2f(pm.x); v[1] *= bf2f(pm.y); v[2] *= bf2f(pm.z); v[3] *= bf2f(pm.w);
      }
      if (bias) {
        float4 bi = *(const float4*)&bias[nb];
        v[0] += bi.x; v[1] += bi.y; v[2] += bi.z; v[3] += bi.w;
      }
      if (resid) {
        ushort4 rd = *(const ushort4*)&resid[(long)g * sO + off];
        v[0] += bf2f(rd.x); v[1] += bf2f(rd.y); v[2] += bf2f(rd.z); v[3] += bf2f(rd.w);
      }
      if (act == 1) {
#pragma unroll
        for (int r = 0; r < 4; ++r) v[r] = fmaxf(v[r], 0.f);
      } else if (act == 2) {
#pragma unroll
        for (int r = 0; r < 4; ++r) v[r] = fmaxf(v[r], 0.f) + 1.f;
      }
      ushort4 o; o.x = f2bf(v[0]); o.y = f2bf(v[1]); o.z = f2bf(v[2]); o.w = f2bf(v[3]);
      *(ushort4*)&Og[off] = o;
    }
  }
}

// fp32 -> bf16 batched casts: 7 proj weights (262144 each) in one launch
__global__ __launch_bounds__(256) void cast7(
    const float* a0, const float* a1, const float* a2, const float* a3,
    const float* a4, const float* a5, const float* a6, u16* __restrict__ dst)
{
  int w = blockIdx.y;
  const float* s = w == 0 ? a0 : w == 1 ? a1 : w == 2 ? a2 : w == 3 ? a3
                 : w == 4 ? a4 : w == 5 ? a5 : a6;
  long i = (long)blockIdx.x * 256 + threadIdx.x;
  dst[(long)w * SZW + i] = f2bf(s[i]);
}

// 4 FFN weights (1048576 each) in one launch
__global__ __launch_bounds__(256) void cast4(
    const float* a0, const float* a1, const float* a2, const float* a3,
    u16* __restrict__ dst)
{
  int w = blockIdx.y;
  const float* s = w == 0 ? a0 : w == 1 ? a1 : w == 2 ? a2 : a3;
  long i = (long)blockIdx.x * 256 + threadIdx.x;
  dst[(long)w * 1048576 + i] = f2bf(s[i]);
}

// gxT[gp*8+b][n][c] = feat[b][c][4n+gp]  (fp32 -> bf16). grid(32,16,8) block(32,8)
__global__ __launch_bounds__(256) void gather_feat(
    const float* __restrict__ feat, u16* __restrict__ gxT)
{
  __shared__ float t[32][132];
  int b = blockIdx.z, c0 = blockIdx.y * 32, nf0 = blockIdx.x * 128;
  int tx = threadIdx.x, ty = threadIdx.y;
  for (int r = ty; r < 32; r += 8)
    *(float4*)&t[r][tx * 4] = *(const float4*)&feat[((long)b * 512 + c0 + r) * 4096 + nf0 + tx * 4];
  __syncthreads();
  int n0o = nf0 >> 2;
  for (int gp = 0; gp < 4; ++gp) {
    long gbase = (long)(gp * 8 + b) * kPLANE;
    for (int jr = ty; jr < 32; jr += 8)
      gxT[gbase + (long)(n0o + jr) * 512 + c0 + tx] = f2bf(t[tx][jr * 4 + gp]);
  }
}

// out[g][c][n] = in[g][n][c] * (alpha ? alpha[g][n] : 1).
// 64x64 tile, ushort2 I/O (4B/lane). grid(16, 8, G) block(32,8)
__global__ __launch_bounds__(256) void transpose_b(
    const u16* __restrict__ in, u16* __restrict__ out, const float* __restrict__ alpha)
{
  int g = blockIdx.z;
  const u16* I = in + (long)g * kPLANE;
  u16* O = out + (long)g * kPLANE;
  __shared__ u16 t[64][66];
  int n0 = blockIdx.x * 64, c0 = blockIdx.y * 64;
  int tx = threadIdx.x, ty = threadIdx.y;
  for (int r = ty; r < 64; r += 8)
    *(ushort2*)&t[r][tx * 2] = *(const ushort2*)&I[(long)(n0 + r) * 512 + c0 + tx * 2];
  __syncthreads();
  float al0 = 1.f, al1 = 1.f;
  if (alpha) {
    al0 = alpha[(long)g * 1024 + n0 + tx * 2];
    al1 = alpha[(long)g * 1024 + n0 + tx * 2 + 1];
  }
  for (int r = ty; r < 64; r += 8) {
    ushort2 wv;
    wv.x = f2bf(bf2f(t[tx * 2][r]) * al0);
    wv.y = f2bf(bf2f(t[tx * 2 + 1][r]) * al1);
    *(ushort2*)&O[(long)(c0 + r) * 1024 + n0 + tx * 2] = wv;
  }
}

// colsum stage 1: part[g*8+ch][c] = sum_{n in chunk ch} X[g][n][c]*alpha?
// grid(2, 8, G) block 256
__global__ __launch_bounds__(256) void colsum1(
    const u16* __restrict__ X, long sX, const float* __restrict__ alpha,
    float* __restrict__ part)
{
  int g = blockIdx.z, ch = blockIdx.y;
  int c = blockIdx.x * 256 + threadIdx.x;
  const u16* Xg = X + (long)g * sX;
  int nb = ch * 128;
  float s = 0.f;
  for (int i = 0; i < 128; ++i) {
    int n = nb + i;
    s += bf2f(Xg[(long)n * 512 + c]) * (alpha ? alpha[(long)g * 1024 + n] : 1.f);
  }
  part[(long)(g * 8 + ch) * 512 + c] = s;
}

// colsum stage 2: out[g][c] = scale * sum_ch part[g*8+ch][c]. grid(2, G)
__global__ __launch_bounds__(256) void colsum2(
    const float* __restrict__ part, float* __restrict__ out, float scale)
{
  int g = blockIdx.y;
  int c = blockIdx.x * 256 + threadIdx.x;
  float s = 0.f;
#pragma unroll
  for (int ch = 0; ch < 8; ++ch) s += part[(long)(g * 8 + ch) * 512 + c];
  out[(long)g * 512 + c] = s * scale;
}

// out[g][n] = f( sum_c X[g][n][c] * w[(g&wmask)][c] ). mode1: 1/(x+1e-6). grid(256,G)
__global__ __launch_bounds__(256) void rowdot(
    const u16* __restrict__ X, long sX, const float* __restrict__ w, int wmask,
    float* __restrict__ out, int mode)
{
  int g = blockIdx.y;
  int n = blockIdx.x * 4 + (threadIdx.x >> 6);
  int L = threadIdx.x & 63;
  const u16* row = X + (long)g * sX + (long)n * 512;
  short8 xv = *(const short8*)&row[L * 8];
  const float* wg = w + (long)(g & wmask) * 512;
  float4 w0 = *(const float4*)&wg[L * 8];
  float4 w1 = *(const float4*)&wg[L * 8 + 4];
  float s = bf2f((u16)xv[0]) * w0.x + bf2f((u16)xv[1]) * w0.y +
            bf2f((u16)xv[2]) * w0.z + bf2f((u16)xv[3]) * w0.w +
            bf2f((u16)xv[4]) * w1.x + bf2f((u16)xv[5]) * w1.y +
            bf2f((u16)xv[6]) * w1.z + bf2f((u16)xv[7]) * w1.w;
#pragma unroll
  for (int off = 32; off >= 1; off >>= 1) s += __shfl_down(s, off);
  if (L == 0) out[(long)g * 1024 + n] = mode ? 1.f / (s + 1e-6f) : s;
}

// alpha[g][n] = softmax_n(sc[g])[n] * 1024. grid(G)
__global__ __launch_bounds__(256) void softmax_row(
    const float* __restrict__ sc, float* __restrict__ out)
{
  int g = blockIdx.x, tid = threadIdx.x;
  const float* s = sc + (long)g * 1024;
  float* o = out + (long)g * 1024;
  __shared__ float red[256];
  float lm = -3.4e38f;
  for (int n = tid; n < 1024; n += 256) lm = fmaxf(lm, s[n]);
  red[tid] = lm; __syncthreads();
  for (int st = 128; st; st >>= 1) { if (tid < st) red[tid] = fmaxf(red[tid], red[tid + st]); __syncthreads(); }
  float mx = red[0]; __syncthreads();
  float ls = 0.f;
  for (int n = tid; n < 1024; n += 256) ls += __expf(s[n] - mx);
  red[tid] = ls; __syncthreads();
  for (int st = 128; st; st >>= 1) { if (tid < st) red[tid] += red[tid + st]; __syncthreads(); }
  float inv = 1024.f / red[0];
  for (int n = tid; n < 1024; n += 256) o[n] = __expf(s[n] - mx) * inv;
}

// Wave-per-row LayerNorm over 512-wide rows. 4 rows/block, 16B/lane I/O,
// shuffle butterfly reduce, zero barriers. grid = rows/4.
__global__ __launch_bounds__(256) void ln_rows(
    const u16* __restrict__ X, const float* __restrict__ gamma,
    const float* __restrict__ beta, u16* __restrict__ Out, int relu)
{
  long m = (long)blockIdx.x * 4 + (threadIdx.x >> 6);
  int L = threadIdx.x & 63;
  const u16* x = X + m * 512;
  u16* o = Out + m * 512;
  short8 xv = *(const short8*)&x[L * 8];
  float v[8];
#pragma unroll
  for (int j = 0; j < 8; ++j) v[j] = bf2f((u16)xv[j]);
  float s = v[0] + v[1] + v[2] + v[3] + v[4] + v[5] + v[6] + v[7];
#pragma unroll
  for (int off = 32; off >= 1; off >>= 1) s += __shfl_xor(s, off);
  float mu = s * (1.f / 512.f);
  float ss = 0.f;
#pragma unroll
  for (int j = 0; j < 8; ++j) { v[j] -= mu; ss += v[j] * v[j]; }
#pragma unroll
  for (int off = 32; off >= 1; off >>= 1) ss += __shfl_xor(ss, off);
  float rs = rsqrtf(ss * (1.f / 512.f) + 1e-6f);
  float4 g0 = *(const float4*)&gamma[L * 8];
  float4 g1 = *(const float4*)&gamma[L * 8 + 4];
  float4 b0 = *(const float4*)&beta[L * 8];
  float4 b1 = *(const float4*)&beta[L * 8 + 4];
  float ov[8];
  ov[0] = v[0] * rs * g0.x + b0.x; ov[1] = v[1] * rs * g0.y + b0.y;
  ov[2] = v[2] * rs * g0.z + b0.z; ov[3] = v[3] * rs * g0.w + b0.w;
  ov[4] = v[4] * rs * g1.x + b1.x; ov[5] = v[5] * rs * g1.y + b1.y;
  ov[6] = v[6] * rs * g1.z + b1.z; ov[7] = v[7] * rs * g1.w + b1.w;
  if (relu) {
#pragma unroll
    for (int j = 0; j < 8; ++j) ov[j] = fmaxf(ov[j], 0.f);
  }
  short8 r;
#pragma unroll
  for (int j = 0; j < 8; ++j) r[j] = (short)f2bf(ov[j]);
  *(short8*)&o[L * 8] = r;
}

// Fused: Out[g2][m] = relu(LN(X[srcrow(g2,m)])) with the gather_x2 row map.
// Wave-per-row. grid = 32768/4 = 8192.
__global__ __launch_bounds__(256) void ln_gather(
    const u16* __restrict__ X, const float* __restrict__ gamma,
    const float* __restrict__ beta, u16* __restrict__ Out)
{
  long bid = (long)blockIdx.x * 4 + (threadIdx.x >> 6);
  int L = threadIdx.x & 63;
  int g2 = (int)(bid >> 10), m = (int)(bid & 1023);
  long src = ((long)((m & 3) * 8 + (g2 & 7)) * 1024 + (g2 >> 3) * 256 + (m >> 2)) * 512;
  const u16* x = X + src;
  u16* o = Out + bid * 512;
  short8 xv = *(const short8*)&x[L * 8];
  float v[8];
#pragma unroll
  for (int j = 0; j < 8; ++j) v[j] = bf2f((u16)xv[j]);
  float s = v[0] + v[1] + v[2] + v[3] + v[4] + v[5] + v[6] + v[7];
#pragma unroll
  for (int off = 32; off >= 1; off >>= 1) s += __shfl_xor(s, off);
  float mu = s * (1.f / 512.f);
  float ss = 0.f;
#pragma unroll
  for (int j = 0; j < 8; ++j) { v[j] -= mu; ss += v[j] * v[j]; }
#pragma unroll
  for (int off = 32; off >= 1; off >>= 1) ss += __shfl_xor(ss, off);
  float rs = rsqrtf(ss * (1.f / 512.f) + 1e-6f);
  float4 g0 = *(const float4*)&gamma[L * 8];
  float4 g1 = *(const float4*)&gamma[L * 8 + 4];
  float4 b0 = *(const float4*)&beta[L * 8];
  float4 b1 = *(const float4*)&beta[L * 8 + 4];
  float ov[8];
  ov[0] = v[0] * rs * g0.x + b0.x; ov[1] = v[1] * rs * g0.y + b0.y;
  ov[2] = v[2] * rs * g0.z + b0.z; ov[3] = v[3] * rs * g0.w + b0.w;
  ov[4] = v[4] * rs * g1.x + b1.x; ov[5] = v[5] * rs * g1.y + b1.y;
  ov[6] = v[6] * rs * g1.z + b1.z; ov[7] = v[7] * rs * g1.w + b1.w;
  short8 r;
#pragma unroll
  for (int j = 0; j < 8; ++j) r[j] = (short)f2bf(fmaxf(ov[j], 0.f));
  *(short8*)&o[L * 8] = r;
}

// ybar = mean over 24 planes, 2 elems/thread (bf16 in, fp32 out). grid 1024
__global__ __launch_bounds__(256) void ybar_k(
    const u16* __restrict__ Y, float* __restrict__ yb)
{
  long idx = ((long)blockIdx.x * 256 + threadIdx.x) * 2;
  float s0 = 0.f, s1 = 0.f;
#pragma unroll
  for (int g = 0; g < 24; ++g) {
    ushort2 u = *(const ushort2*)&Y[(long)g * kPLANE + idx];
    s0 += bf2f(u.x); s1 += bf2f(u.y);
  }
  float2 o; o.x = s0 * (1.f / 24.f); o.y = s1 * (1.f / 24.f);
  *(float2*)&yb[idx] = o;
}

// Fused h_first + LN(cg1): row m=(b,n); h = gx2[m] + yb[n]*phiF[m]; out = LN(h).
// Wave-per-row, saves the 16MB h_first round trip. grid = 8192/4 = 2048.
__global__ __launch_bounds__(256) void hfirst_ln(
    const u16* __restrict__ gx2, const u16* __restrict__ phiF,
    const float* __restrict__ yb, const float* __restrict__ gamma,
    const float* __restrict__ beta, u16* __restrict__ Out)
{
  long m = (long)blockIdx.x * 4 + (threadIdx.x >> 6);
  int L = threadIdx.x & 63;
  long off = m * 512 + L * 8;
  long yoff = (m & 1023) * 512 + L * 8;
  short8 a8 = *(const short8*)&gx2[off];
  short8 f8 = *(const short8*)&phiF[off];
  float4 y0 = *(const float4*)&yb[yoff];
  float4 y1 = *(const float4*)&yb[yoff + 4];
  float v[8];
  v[0] = bf2f((u16)a8[0]) + y0.x * bf2f((u16)f8[0]);
  v[1] = bf2f((u16)a8[1]) + y0.y * bf2f((u16)f8[1]);
  v[2] = bf2f((u16)a8[2]) + y0.z * bf2f((u16)f8[2]);
  v[3] = bf2f((u16)a8[3]) + y0.w * bf2f((u16)f8[3]);
  v[4] = bf2f((u16)a8[4]) + y1.x * bf2f((u16)f8[4]);
  v[5] = bf2f((u16)a8[5]) + y1.y * bf2f((u16)f8[5]);
  v[6] = bf2f((u16)a8[6]) + y1.z * bf2f((u16)f8[6]);
  v[7] = bf2f((u16)a8[7]) + y1.w * bf2f((u16)f8[7]);
  float s = v[0] + v[1] + v[2] + v[3] + v[4] + v[5] + v[6] + v[7];
#pragma unroll
  for (int off2 = 32; off2 >= 1; off2 >>= 1) s += __shfl_xor(s, off2);
  float mu = s * (1.f / 512.f);
  float ss = 0.f;
#pragma unroll
  for (int j = 0; j < 8; ++j) { v[j] -= mu; ss += v[j] * v[j]; }
#pragma unroll
  for (int off2 = 32; off2 >= 1; off2 >>= 1) ss += __shfl_xor(ss, off2);
  float rs = rsqrtf(ss * (1.f / 512.f) + 1e-6f);
  float4 g0 = *(const float4*)&gamma[L * 8];
  float4 g1 = *(const float4*)&gamma[L * 8 + 4];
  float4 b0 = *(const float4*)&beta[L * 8];
  float4 b1 = *(const float4*)&beta[L * 8 + 4];
  float ov[8];
  ov[0] = v[0] * rs * g0.x + b0.x; ov[1] = v[1] * rs * g0.y + b0.y;
  ov[2] = v[2] * rs * g0.z + b0.z; ov[3] = v[3] * rs * g0.w + b0.w;
  ov[4] = v[4] * rs * g1.x + b1.x; ov[5] = v[5] * rs * g1.y + b1.y;
  ov[6] = v[6] * rs * g1.z + b1.z; ov[7] = v[7] * rs * g1.w + b1.w;
  short8 r;
#pragma unroll
  for (int j = 0; j < 8; ++j) r[j] = (short)f2bf(ov[j]);
  *(short8*)&Out[off] = r;
}

// out[b][c][gp2*1024+m] = (gp2==0 ? crossT[b] : gx2T[g2])[m][c]. grid(32,16,32) block(32,8)
__global__ __launch_bounds__(256) void assemble_t(
    const u16* __restrict__ gx2T, const u16* __restrict__ crossT,
    float* __restrict__ out)
{
  int g2 = blockIdx.z, gp2 = g2 >> 3, b = g2 & 7;
  const u16* S = (gp2 == 0) ? crossT + (long)b * kPLANE : gx2T + (long)g2 * kPLANE;
  __shared__ u16 t[32][33];
  int m0 = blockIdx.x * 32, c0 = blockIdx.y * 32;
  int tx = threadIdx.x, ty = threadIdx.y;
  for (int r = ty; r < 32; r += 8) t[r][tx] = S[(long)(m0 + r) * 512 + c0 + tx];
  __syncthreads();
  for (int r = ty; r < 32; r += 8)
    out[((long)b * 512 + c0 + r) * 4096 + gp2 * 1024 + m0 + tx] = bf2f(t[tx][r]);
}

extern "C" void kernel_launch(void* const* d_in, const int* in_sizes, int n_in,
                              void* d_out, int out_size, void* d_ws, size_t ws_size,
                              hipStream_t stream)
{
  const float* feat = (const float*)d_in[0];
  const float* tg1 = (const float*)d_in[4];  const float* tb1 = (const float*)d_in[5];
  const float* tf1b = (const float*)d_in[7];
  const float* tf2b = (const float*)d_in[9];
  const float* tg2 = (const float*)d_in[10]; const float* tb2 = (const float*)d_in[11];
  const float* cg1 = (const float*)d_in[16]; const float* cb1 = (const float*)d_in[17];
  const float* cf1b = (const float*)d_in[19];
  const float* cf2b = (const float*)d_in[21];
  const float* cg2 = (const float*)d_in[22]; const float* cb2 = (const float*)d_in[23];

  // ---- ws layout (peak 112 MiB) ----
  char* wsb = (char*)d_ws;
  u16* WP = (u16*)wsb;                 // 7 proj weights (d,c) bf16: 3.5 MiB
  u16* WF = (u16*)(wsb + 4 * MB);      // 4 FFN weights bf16: 8 MiB
  float* SM = (float*)(wsb + 12 * MB); // fp32 smalls
  float* QG = SM;                      // 32*512
  float* SC = SM + 16384;              // 32*1024
  float* AL = SM + 49152;              // 32*1024
  float* KS = SM + 81920;              // 32*512
  float* Zb = SM + 98304;              // 32*1024
  float* ZR = SM + 131072;             // 24*1024
  float* YB = SM + 155648;             // 1024*512 fp32 (ends 679936)
  float* PART = SM + 688128;           // colsum partials 32*8*512 (ends 819200)
  u16* P2 = (u16*)(wsb + 16 * MB);     // 32 planes
  u16* P3 = (u16*)(wsb + 48 * MB);     // 32 planes
  u16* P4 = (u16*)(wsb + 80 * MB);     // 32 planes (ends 112 MiB)

  // ---- d_out (64 MiB) doubles as scratch until final assemble ----
  char* ob = (char*)d_out;
  u16* KV  = (u16*)ob;                 // SA kvT: 16 MiB
  u16* GXT = (u16*)(ob + 16 * MB);     // gxT: 32 MiB (dead after y GEMM)
  u16* HID = (u16*)ob;                 // FFN hidden chunk: 64 MiB (kv+gxT dead)
  u16* KV2 = (u16*)(ob + 32 * MB);     // cross kvT: 4 MiB
  u16* PHF = (u16*)(ob + 36 * MB);     // phi_first: 8 MiB
  u16* K0S = (u16*)(ob + 44 * MB);     // k0*alpha (c,n): 8 MiB
  u16* V0S = (u16*)(ob + 52 * MB);     // v0 (c,n): 8 MiB

  u16 *WPqk = WP,           *WPv  = WP + SZW,     *WPphi = WP + 2 * SZW,
      *WPcq = WP + 3 * SZW, *WPck = WP + 4 * SZW, *WPcv  = WP + 5 * SZW,
      *WPcphi = WP + 6 * SZW;
  u16 *WF1 = WF, *WF2 = WF + 1048576, *WF3 = WF + 2097152, *WF4 = WF + 3145728;

  dim3 b256(256), bT(32, 8);
  const float rsc = 1.0f / sqrtf(512.0f);
  const long PL = kPLANE;

  // 0. weight casts, batched
  cast7<<<dim3(1024, 7), b256, 0, stream>>>(
      (const float*)d_in[1], (const float*)d_in[2], (const float*)d_in[3],
      (const float*)d_in[12], (const float*)d_in[13], (const float*)d_in[14],
      (const float*)d_in[15], WP);
  cast4<<<dim3(4096, 4), b256, 0, stream>>>(
      (const float*)d_in[6], (const float*)d_in[8],
      (const float*)d_in[18], (const float*)d_in[20], WF);

  // ---------------- SA block (all tensors (g,n,c) T-layout) ----------------
  gather_feat<<<dim3(32, 16, 8), bT, 0, stream>>>(feat, GXT);
  // qT = phi(gxT . Wqk^T)
  gemm_mfma<<<dim3(4, 8, 32), b256, 0, stream>>>(GXT, PL, 31, WPqk, 0, 0, P2, PL,
      1024, 512, 512, 1.f, 2, nullptr, nullptr, 0, nullptr, nullptr);
  colsum1<<<dim3(2, 8, 32), b256, 0, stream>>>(P2, PL, nullptr, PART);
  colsum2<<<dim3(2, 32), b256, 0, stream>>>(PART, QG, 1.f / 1024.f);
  rowdot<<<dim3(256, 32), b256, 0, stream>>>(P2, PL, QG, 31, SC, 0);
  softmax_row<<<32, b256, 0, stream>>>(SC, AL);
  // vT, then transpose v and k'=q*alpha into (c,n) layout for kv GEMM
  gemm_mfma<<<dim3(4, 8, 32), b256, 0, stream>>>(GXT, PL, 31, WPv, 0, 0, P3, PL,
      1024, 512, 512, 1.f, 0, nullptr, nullptr, 0, nullptr, nullptr);
  transpose_b<<<dim3(16, 8, 32), bT, 0, stream>>>(P3, P4, nullptr);  // v
  transpose_b<<<dim3(16, 8, 32), bT, 0, stream>>>(P2, P3, AL);       // k'
  // kvT[d][c] = sum_n v[d][n] k'[c][n] * rsc
  gemm_mfma<<<dim3(4, 4, 32), b256, 0, stream>>>(P4, PL, 31, P3, PL, 31, KV, SZW,
      512, 512, 1024, rsc, 0, nullptr, nullptr, 0, nullptr, nullptr);
  colsum1<<<dim3(2, 8, 32), b256, 0, stream>>>(P2, PL, AL, PART);
  colsum2<<<dim3(2, 32), b256, 0, stream>>>(PART, KS, 1.f);
  rowdot<<<dim3(256, 32), b256, 0, stream>>>(P2, PL, KS, 31, Zb, 1);
  // phixT
  gemm_mfma<<<dim3(4, 8, 32), b256, 0, stream>>>(GXT, PL, 31, WPphi, 0, 0, P4, PL,
      1024, 512, 512, 1.f, 0, nullptr, nullptr, 0, nullptr, nullptr);
  // h_preT = qT.kvT * z[n] * phixT + gxT
  gemm_mfma<<<dim3(4, 8, 32), b256, 0, stream>>>(P2, PL, 31, KV, SZW, 31, P3, PL,
      1024, 512, 512, 1.f, 0, nullptr, Zb, 1024, P4, GXT);
  ln_rows<<<8192, b256, 0, stream>>>(P3, tg1, tb1, P2, 0);
  // FFN 512->2048->512, 2 chunks of 16384 rows (HID = full 64 MiB d_out)
  for (int ch = 0; ch < 2; ++ch) {
    const u16* Hc = P2 + (long)ch * 16 * PL;
    gemm_mfma<<<dim3(16, 128, 1), b256, 0, stream>>>(Hc, 0, 0, WF1, 0, 0, HID, 0,
        16384, 2048, 512, 1.f, 1, tf1b, nullptr, 0, nullptr, nullptr);
    gemm_mfma<<<dim3(4, 128, 1), b256, 0, stream>>>(HID, 0, 0, WF2, 0, 0,
        P3 + (long)ch * 16 * PL, 0, 16384, 512, 2048, 1.f, 0, tf2b, nullptr, 0, nullptr, Hc);
  }
  ln_gather<<<8192, b256, 0, stream>>>(P3, tg2, tb2, P4);         // t_saT -> gx2T fused

  // ---------------- cross block ----------------
  gemm_mfma<<<dim3(4, 8, 24), b256, 0, stream>>>(P4 + 8 * PL, PL, 31, WPcq, 0, 0, P2, PL,
      1024, 512, 512, 1.f, 2, nullptr, nullptr, 0, nullptr, nullptr);        // q_restT
  gemm_mfma<<<dim3(4, 8, 24), b256, 0, stream>>>(P4 + 8 * PL, PL, 31, WPcphi, 0, 0, P3, PL,
      1024, 512, 512, 1.f, 0, nullptr, nullptr, 0, nullptr, nullptr);        // phi_restT
  gemm_mfma<<<dim3(4, 8, 8), b256, 0, stream>>>(P4, PL, 31, WPck, 0, 0, P2 + 24 * PL, PL,
      1024, 512, 512, 1.f, 2, nullptr, nullptr, 0, nullptr, nullptr);        // k0T
  gemm_mfma<<<dim3(4, 8, 8), b256, 0, stream>>>(P4, PL, 31, WPcv, 0, 0, P3 + 24 * PL, PL,
      1024, 512, 512, 1.f, 0, nullptr, nullptr, 0, nullptr, nullptr);        // v0T
  gemm_mfma<<<dim3(4, 8, 8), b256, 0, stream>>>(P4, PL, 31, WPcphi, 0, 0, PHF, PL,
      1024, 512, 512, 1.f, 0, nullptr, nullptr, 0, nullptr, nullptr);        // phi_firstT
  colsum1<<<dim3(2, 8, 8), b256, 0, stream>>>(P2 + 24 * PL, PL, nullptr, PART);
  colsum2<<<dim3(2, 8), b256, 0, stream>>>(PART, QG, 1.f / 1024.f);
  rowdot<<<dim3(256, 8), b256, 0, stream>>>(P2 + 24 * PL, PL, QG, 7, SC, 0);
  softmax_row<<<8, b256, 0, stream>>>(SC, AL);
  transpose_b<<<dim3(16, 8, 8), bT, 0, stream>>>(P2 + 24 * PL, K0S, AL);  // k0'
  transpose_b<<<dim3(16, 8, 8), bT, 0, stream>>>(P3 + 24 * PL, V0S, nullptr);
  gemm_mfma<<<dim3(4, 4, 8), b256, 0, stream>>>(V0S, PL, 31, K0S, PL, 31, KV2, SZW,
      512, 512, 1024, rsc, 0, nullptr, nullptr, 0, nullptr, nullptr);
  colsum1<<<dim3(2, 8, 8), b256, 0, stream>>>(P2 + 24 * PL, PL, AL, PART);
  colsum2<<<dim3(2, 8), b256, 0, stream>>>(PART, KS, 1.f);
  rowdot<<<dim3(256, 24), b256, 0, stream>>>(P2, PL, KS, 7, ZR, 1);
  // y_restT = q_restT.kvT2[g&7] * z[n] * phi_restT  (in-place into P3)
  gemm_mfma<<<dim3(4, 8, 24), b256, 0, stream>>>(P2, PL, 31, KV2, SZW, 7, P3, PL,
      1024, 512, 512, 1.f, 0, nullptr, ZR, 1024, P3, nullptr);
  ybar_k<<<1024, b256, 0, stream>>>(P3, YB);
  hfirst_ln<<<2048, b256, 0, stream>>>(P4, PHF, YB, cg1, cb1, P3 + 24 * PL);
  gemm_mfma<<<dim3(16, 64, 1), b256, 0, stream>>>(P3 + 24 * PL, 0, 0, WF3, 0, 0, HID, 0,
      8192, 2048, 512, 1.f, 1, cf1b, nullptr, 0, nullptr, nullptr);
  gemm_mfma<<<dim3(4, 64, 1), b256, 0, stream>>>(HID, 0, 0, WF4, 0, 0, P2 + 24 * PL, 0,
      8192, 512, 2048, 1.f, 0, cf2b, nullptr, 0, nullptr, P3 + 24 * PL);
  ln_rows<<<2048, b256, 0, stream>>>(P2 + 24 * PL, cg2, cb2, P3 + 24 * PL, 1); // crossT
  assemble_t<<<dim3(32, 16, 32), bT, 0, stream>>>(P4, P3 + 24 * PL, (float*)d_out);
}